// Round 10
// baseline (39734.735 us; speedup 1.0000x reference)
//
#include <hip/hip_runtime.h>

#define BB 512
#define TT 128
#define EE 512
#define HH 256
#define VV 39
#define H3 768
#define H2 512
#define TM1 127
#define NEGF (-3.402823466e38f)

typedef unsigned short u16;
typedef unsigned int u32;
typedef __attribute__((ext_vector_type(8))) short s16x8;
typedef __attribute__((ext_vector_type(4))) float f32x4;
typedef __attribute__((ext_vector_type(2))) unsigned int u32x2;
typedef __attribute__((ext_vector_type(4))) unsigned int u32x4;

__device__ __forceinline__ float b2f(u16 u){ u32 x=((u32)u)<<16; return __uint_as_float(x); }
__device__ __forceinline__ u16 f2b(float f){ u32 x=__float_as_uint(f); u32 r=(x+0x7fffu+((x>>16)&1u))>>16; return (u16)r; }
__device__ __forceinline__ float sigm(float x){ return 1.f/(1.f+__expf(-x)); }
__device__ __forceinline__ float tanh1(float x){ float t=__expf(2.f*x); return 1.f-2.f/(t+1.f); }
__device__ __forceinline__ float bfl(u32 u){ return __uint_as_float(u<<16); }
__device__ __forceinline__ float bfh(u32 u){ return __uint_as_float(u & 0xffff0000u); }

#define MFMA __builtin_amdgcn_mfma_f32_16x16x32_bf16

// ---------------------------------------------------------------------------
__global__ __launch_bounds__(256) void k_tables(
    const float* __restrict__ src_emb, const float* __restrict__ trg_emb,
    const float* __restrict__ Wih_f, const float* __restrict__ bih_f,
    const float* __restrict__ Wih_b, const float* __restrict__ bih_b,
    const float* __restrict__ dec_Wih, const float* __restrict__ dec_bih,
    const float* __restrict__ pre_W,
    float* __restrict__ tab_gi_f, float* __restrict__ tab_gi_b,
    float* __restrict__ tab_dec, float* __restrict__ tab_pre)
{
  int v = blockIdx.x;
  int y = blockIdx.y;
  int tid = threadIdx.x;
  if (y < 9){
    int seg = y/3, part = y%3;
    int n = part*256 + tid;
    const float* emb; const float* W; const float* bias; float* out; int ldw;
    if (seg==0){ emb=src_emb; W=Wih_f; bias=bih_f; out=tab_gi_f; ldw=EE; }
    else if (seg==1){ emb=src_emb; W=Wih_b; bias=bih_b; out=tab_gi_b; ldw=EE; }
    else { emb=trg_emb; W=dec_Wih; bias=dec_bih; out=tab_dec; ldw=EE+H2; }
    float acc = bias[n];
    const float* er = emb + (size_t)v*EE;
    const float* wr = W + (size_t)n*ldw;
    for (int k=0;k<EE;k++) acc += er[k]*wr[k];
    out[(size_t)v*H3 + n] = acc;
  } else {
    int n = tid;
    float acc = 0.f;
    const float* er = trg_emb + (size_t)v*EE;
    const float* wr = pre_W + (size_t)n*1280;
    for (int k=0;k<EE;k++) acc += er[k]*wr[k];
    tab_pre[(size_t)v*HH + n] = acc;
  }
}

// fp32->bf16 weight prep. Encoder weights + Wk row-major; decoder GEMV
// weights TRANSPOSED to [K][N] for coalesced per-column access. grid(5440).
__global__ __launch_bounds__(256) void k_cvt_all(
    const float* __restrict__ eWhh_f, const float* __restrict__ eWhh_b,
    const float* __restrict__ Wk, const float* __restrict__ Wq,
    const float* __restrict__ dWhh, const float* __restrict__ dWih,
    const float* __restrict__ preW, const float* __restrict__ genW,
    u16* __restrict__ o1, u16* __restrict__ o2, u16* __restrict__ o3,
    u16* __restrict__ o4, u16* __restrict__ o5, u16* __restrict__ o6,
    u16* __restrict__ o7, u16* __restrict__ o8, u16* __restrict__ o9)
{
  int idx = blockIdx.x*256 + threadIdx.x;
  if (idx < 196608){                      // o1: eWhh_f row-major copy
    o1[idx] = f2b(eWhh_f[idx]);
  } else if (idx < 393216){               // o2: eWhh_b
    int rel = idx-196608; o2[rel] = f2b(eWhh_b[rel]);
  } else if (idx < 524288){               // o3: Wk row-major (256x512)
    int rel = idx-393216; o3[rel] = f2b(Wk[rel]);
  } else if (idx < 589824){               // o4: wqT [256][256]
    int rel = idx-524288; int k=rel>>8, n=rel&255;
    o4[rel] = f2b(Wq[(size_t)n*HH + k]);
  } else if (idx < 786432){               // o5: whhT [256][768]
    int rel = idx-589824; int k=rel/768, n=rel-k*768;
    o5[rel] = f2b(dWhh[(size_t)n*HH + k]);
  } else if (idx < 1179648){              // o6: wihcT [512][768]
    int rel = idx-786432; int k=rel/768, n=rel-k*768;
    o6[rel] = f2b(dWih[(size_t)n*1024 + 512 + k]);
  } else if (idx < 1310720){              // o7: wpcT [512][256]
    int rel = idx-1179648; int k=rel>>8, n=rel&255;
    o7[rel] = f2b(preW[(size_t)n*1280 + 768 + k]);
  } else if (idx < 1376256){              // o8: wphT [256][256]
    int rel = idx-1310720; int k=rel>>8, n=rel&255;
    o8[rel] = f2b(preW[(size_t)n*1280 + 512 + k]);
  } else if (idx < 1392640){              // o9: wgenT [256][64] (pad 39->64)
    int rel = idx-1376256; int k=rel>>6, n=rel&63;
    o9[rel] = (n<VV)? f2b(genW[(size_t)n*HH + k]) : (u16)0;
  }
}

// ---------------------------------------------------------------------------
// WHOLE encoder in one kernel, zero grid barriers. grid(32), block 512.
__global__ __launch_bounds__(512) void k_enc_all(const int* __restrict__ input,
    const u16* __restrict__ wb_f, const u16* __restrict__ wb_b,
    const float* __restrict__ bhh_f, const float* __restrict__ bhh_b,
    const float* __restrict__ tab_f, const float* __restrict__ tab_b,
    float* __restrict__ h_f, float* __restrict__ h_b, u16* __restrict__ enc_out)
{
  __shared__ float gh[32][772];
  __shared__ u16 hs[32][264];
  int bx = blockIdx.x;
  int dirb = bx>>4, mt = bx&15;
  int m0 = mt*32;
  int tid = threadIdx.x;
  const float* tab = dirb? tab_b : tab_f;
  const float* bhh = dirb? bhh_b : bhh_f;
  const u16* Wb = dirb? wb_b : wb_f;
  int c = tid & 255, rh = tid>>8;
  float b_r=bhh[c], b_z=bhh[c+256], b_n=bhh[c+512];
  float hreg[16];
  #pragma unroll
  for (int r=0;r<16;r++) hreg[r]=0.f;
  int wv = tid>>6, lane = tid&63, l15 = lane&15, kg=(lane>>4)*8;
  int n0w = wv*96;
  float* hOut = dirb? h_b : h_f;

  for (int s=1; s<=TT; s++){
    int tcol = dirb? (TT-s) : (s-1);
    #pragma unroll
    for (int r=0;r<16;r++){
      int row = rh*16 + r;
      int b = m0 + row;
      int tok = input[b*TT + tcol];
      const float* tg = tab + (size_t)tok*H3;
      float g0=0.f, g1=0.f, g2=0.f;
      if (s>1){ g0=gh[row][c]; g1=gh[row][c+256]; g2=gh[row][c+512]; }
      float rg = sigm(tg[c]     + g0 + b_r);
      float zg = sigm(tg[c+256] + g1 + b_z);
      float ng = tanh1(tg[c+512] + rg*(g2 + b_n));
      float hv = (1.f-zg)*ng + zg*hreg[r];
      hreg[r] = hv;
      u16 hb = f2b(hv);
      hs[row][c] = hb;
      enc_out[((size_t)b*TT + tcol)*H2 + (size_t)dirb*HH + c] = hb;
    }
    if (s==TT){
      #pragma unroll
      for (int r=0;r<16;r++)
        hOut[(size_t)(m0+rh*16+r)*HH + c] = hreg[r];
      break;
    }
    __syncthreads();
    f32x4 acc[2][6];
    #pragma unroll
    for (int rt=0;rt<2;rt++)
      #pragma unroll
      for (int nt=0;nt<6;nt++) acc[rt][nt]=(f32x4){0.f,0.f,0.f,0.f};
    const u16* ar0 = &hs[l15][0];
    const u16* ar1 = &hs[16+l15][0];
    for (int ko=0;ko<256;ko+=32){
      s16x8 a0 = *(const s16x8*)(ar0 + ko + kg);
      s16x8 a1 = *(const s16x8*)(ar1 + ko + kg);
      #pragma unroll
      for (int nt=0;nt<6;nt++){
        s16x8 bf = *(const s16x8*)(Wb + (size_t)(n0w+nt*16+l15)*HH + ko + kg);
        acc[0][nt] = MFMA(a0, bf, acc[0][nt], 0,0,0);
        acc[1][nt] = MFMA(a1, bf, acc[1][nt], 0,0,0);
      }
    }
    int q4 = (lane>>4)*4;
    #pragma unroll
    for (int rt=0;rt<2;rt++)
      #pragma unroll
      for (int nt=0;nt<6;nt++){
        int col = n0w + nt*16 + l15;
        #pragma unroll
        for (int j=0;j<4;j++)
          gh[rt*16 + q4 + j][col] = acc[rt][nt][j];
      }
    __syncthreads();
  }
}

// proj_key = enc_out @ Wk^T : MFMA. grid(1024), block 256.
__global__ __launch_bounds__(256) void k_pk(const u16* __restrict__ enc_out,
    const u16* __restrict__ wbk, u16* __restrict__ pk)
{
  int m0 = blockIdx.x*64;
  int tid = threadIdx.x, wv = tid>>6, lane = tid&63;
  int l15 = lane&15, kg = (lane>>4)*8;
  int n0 = wv*64;
  f32x4 acc[4][4];
  #pragma unroll
  for (int rt=0;rt<4;rt++)
    #pragma unroll
    for (int nt=0;nt<4;nt++) acc[rt][nt] = (f32x4){0.f,0.f,0.f,0.f};
  for (int ko=0; ko<512; ko+=32){
    s16x8 a[4], b[4];
    #pragma unroll
    for (int rt=0;rt<4;rt++) a[rt] = *(const s16x8*)(enc_out + (size_t)(m0+rt*16+l15)*H2 + ko + kg);
    #pragma unroll
    for (int nt=0;nt<4;nt++) b[nt] = *(const s16x8*)(wbk + (size_t)(n0+nt*16+l15)*H2 + ko + kg);
    #pragma unroll
    for (int rt=0;rt<4;rt++)
      #pragma unroll
      for (int nt=0;nt<4;nt++)
        acc[rt][nt] = MFMA(a[rt], b[nt], acc[rt][nt], 0,0,0);
  }
  #pragma unroll
  for (int rt=0;rt<4;rt++){
    int rbase = m0 + rt*16 + (lane>>4)*4;
    #pragma unroll
    for (int nt=0;nt<4;nt++){
      int col = n0 + nt*16 + l15;
      #pragma unroll
      for (int j=0;j<4;j++)
        pk[(size_t)(rbase+j)*HH + col] = f2b(acc[rt][nt][j]);
    }
  }
}

// hidden = tanh([h_f|h_b] @ bridge_W^T + b) -> hst. grid (4,8).
__global__ __launch_bounds__(256) void k_bridge(const float* __restrict__ h_f,
    const float* __restrict__ h_b, const float* __restrict__ bw,
    const float* __restrict__ bb, float* __restrict__ hst)
{
  __shared__ float As[32][68];
  __shared__ float Ws[32][68];
  int n0=blockIdx.x*64, m0=blockIdx.y*64, tid=threadIdx.x;
  int ar=tid>>2, ak=(tid&3)*8;
  int rt=tid>>4, ct=tid&15;
  float acc[4][4];
  #pragma unroll
  for (int j=0;j<4;j++){
    #pragma unroll
    for (int l=0;l<4;l++) acc[j][l]=0.f;
  }
  for (int ko=0;ko<512;ko+=32){
    int k0=ko+ak;
    const float* asrc = (k0<256)? (h_f + (size_t)(m0+ar)*HH + k0)
                                : (h_b + (size_t)(m0+ar)*HH + (k0-256));
    float4 a0=*(const float4*)asrc, a1=*(const float4*)(asrc+4);
    const float* wsrc = bw + (size_t)(n0+ar)*H2 + k0;
    float4 w0=*(const float4*)wsrc, w1=*(const float4*)(wsrc+4);
    __syncthreads();
    As[ak+0][ar]=a0.x; As[ak+1][ar]=a0.y; As[ak+2][ar]=a0.z; As[ak+3][ar]=a0.w;
    As[ak+4][ar]=a1.x; As[ak+5][ar]=a1.y; As[ak+6][ar]=a1.z; As[ak+7][ar]=a1.w;
    Ws[ak+0][ar]=w0.x; Ws[ak+1][ar]=w0.y; Ws[ak+2][ar]=w0.z; Ws[ak+3][ar]=w0.w;
    Ws[ak+4][ar]=w1.x; Ws[ak+5][ar]=w1.y; Ws[ak+6][ar]=w1.z; Ws[ak+7][ar]=w1.w;
    __syncthreads();
    #pragma unroll
    for (int kk=0;kk<32;kk++){
      float4 a=*(const float4*)&As[kk][rt*4];
      float4 w=*(const float4*)&Ws[kk][ct*4];
      float a4[4]={a.x,a.y,a.z,a.w};
      float w4[4]={w.x,w.y,w.z,w.w};
      #pragma unroll
      for (int j=0;j<4;j++){
        #pragma unroll
        for (int l=0;l<4;l++) acc[j][l]+=a4[j]*w4[l];
      }
    }
  }
  #pragma unroll
  for (int j=0;j<4;j++){
    int row=m0+rt*4+j;
    #pragma unroll
    for (int l=0;l<4;l++){
      int col=n0+ct*4+l;
      hst[(size_t)row*HH+col]=tanh1(acc[j][l]+bb[col]);
    }
  }
}

// ---------------------------------------------------------------------------
// Fully block-local decoder. grid(256) x 512 thr. Block owns rows {2bx,2bx+1}
// end-to-end: pk in LDS, enc in VGPRs, all state LDS-resident, zero inter-
// block communication. GEMVs: VALU vs transposed bf16 weights (L2-resident).
#define PHASE_B                                                              \
  for (int pass=0; pass<2; pass++){                                          \
    int v = tid + pass*512;                                                  \
    if (v < 640){                                                            \
      int r = (v>=320)?1:0; int vv = v - r*320;                              \
      const u16* wb; float* op; int nc;                                      \
      if (vv<64){ wb=wqT+4*vv; nc=256; op=&qL[r][4*vv]; }                    \
      else if (vv<256){ wb=whhT+4*(vv-64); nc=768; op=&ghL[r][4*(vv-64)]; }  \
      else { wb=wphT+4*(vv-256); nc=256; op=&phL[r][4*(vv-256)]; }           \
      float a0=0.f,a1=0.f,a2=0.f,a3=0.f;                                     \
      _Pragma("unroll 8")                                                    \
      for (int k=0;k<256;k++){                                               \
        u32x2 w = *(const u32x2*)(wb + (size_t)k*nc);                        \
        float x = hL[r][k];                                                  \
        a0+=bfl(w.x)*x; a1+=bfh(w.x)*x; a2+=bfl(w.y)*x; a3+=bfh(w.y)*x;      \
      }                                                                      \
      op[0]=a0; op[1]=a1; op[2]=a2; op[3]=a3;                                \
    }                                                                        \
  }

__global__ __launch_bounds__(512,2) void k_dec2(
    const int* __restrict__ input, const float* __restrict__ hst,
    const float* __restrict__ tab_dec, const float* __restrict__ tab_pre,
    const float* __restrict__ bhh, const float* __restrict__ We,
    const u16* __restrict__ wqT, const u16* __restrict__ whhT,
    const u16* __restrict__ wihcT, const u16* __restrict__ wpcT,
    const u16* __restrict__ wphT, const u16* __restrict__ wgenT,
    const u16* __restrict__ pk, const u16* __restrict__ enc_out,
    float* __restrict__ nll_part)
{
  __shared__ u16 pkL[2][TT][HH];     // 128 KB, resident all steps
  __shared__ float ctxL[2][H2];
  __shared__ float gicL[2][H3];
  __shared__ float ghL[2][H3];
  __shared__ float hL[2][HH];
  __shared__ float qL[2][HH];
  __shared__ float pcL[2][HH];
  __shared__ float phL[2][HH];
  __shared__ float preL[2][HH];
  __shared__ float aL[2][TT];
  __shared__ int   stokI[2][TT];
  __shared__ float lgtL[2][64];
  __shared__ float nred[2];

  int bx=blockIdx.x, tid=threadIdx.x;
  int wv=tid>>6, lane=tid&63;
  int rowA = bx*2;
  int row4 = wv>>2, wl = wv&3;       // e/ctx: wave -> (row, quarter)
  int rT = tid>>8, cT = tid&255;     // gates/pre: thread -> (row, col)

  // ---- one-time residency loads
  for (int e=tid*8; e<2*TT*HH; e+=512*8)
    *(u32x4*)(&pkL[0][0][0]+e) = *(const u32x4*)(pk + (size_t)rowA*TT*HH + e);
  if (tid<256) stokI[tid>>7][tid&127] = input[(rowA+(tid>>7))*TT + (tid&127)];
  hL[rT][cT] = hst[(size_t)(rowA+rT)*HH + cT];
  u32 encr[TT];                      // enc[row4][t][wl*128+lane*2 ..+1]
  {
    const u16* eb = enc_out + (size_t)(rowA+row4)*TT*H2 + wl*128 + lane*2;
    #pragma unroll
    for (int t=0;t<TT;t++) encr[t] = *(const u32*)(eb + (size_t)t*H2);
  }
  float4 weL = *(const float4*)(We + lane*4);
  float b_r=bhh[cT], b_z=bhh[cT+256], b_n=bhh[cT+512];
  float nlacc = 0.f;
  __syncthreads();

  // ---- bootstrap: q0, gh0 from h0 (phL garbage, unused)
  PHASE_B
  __syncthreads();

  for (int j=0;j<TM1;j++){
    // e[t] = We . tanh(q + pk[t])
    {
      float4 qq = *(const float4*)&qL[row4][lane*4];
      #pragma unroll
      for (int tt=0;tt<32;tt++){
        int t = wl*32 + tt;
        u32x2 pp = *(const u32x2*)&pkL[row4][t][lane*4];
        float s = tanh1(qq.x+bfl(pp.x))*weL.x + tanh1(qq.y+bfh(pp.x))*weL.y
                + tanh1(qq.z+bfl(pp.y))*weL.z + tanh1(qq.w+bfh(pp.y))*weL.w;
        #pragma unroll
        for (int off=32; off; off>>=1) s += __shfl_xor(s,off);
        if (lane==0) aL[row4][t] = stokI[row4][t] ? s : NEGF;
      }
    }
    __syncthreads();
    if (wl==0){    // waves 0,4: softmax for row row4
      float v0 = aL[row4][lane], v1 = aL[row4][64+lane];
      float m = fmaxf(v0,v1);
      #pragma unroll
      for (int off=32; off; off>>=1) m = fmaxf(m, __shfl_xor(m,off));
      float p0 = __expf(v0-m), p1 = __expf(v1-m);
      float s = p0+p1;
      #pragma unroll
      for (int off=32; off; off>>=1) s += __shfl_xor(s,off);
      float inv = 1.f/s;
      aL[row4][lane] = p0*inv; aL[row4][64+lane] = p1*inv;
    }
    __syncthreads();
    // ctx: lane owns 2 dims, all 128 t in registers -> no reduction
    {
      float a0=0.f, a1=0.f;
      #pragma unroll
      for (int t=0;t<TT;t++){
        float a = aL[row4][t];
        a0 += a*bfl(encr[t]); a1 += a*bfh(encr[t]);
      }
      int d = wl*128 + lane*2;
      ctxL[row4][d] = a0; ctxL[row4][d+1] = a1;
    }
    __syncthreads();
    // phase A: gic = ctx@WihcT, pc = ctx@WpcT (K=512)
    {
      const u16* wb; float* op; int nc;
      if (cT<192){ wb = wihcT + 4*cT; nc=768; op=&gicL[rT][4*cT]; }
      else { wb = wpcT + 4*(cT-192); nc=256; op=&pcL[rT][4*(cT-192)]; }
      float a0=0.f,a1=0.f,a2=0.f,a3=0.f;
      #pragma unroll 8
      for (int k=0;k<512;k++){
        u32x2 w = *(const u32x2*)(wb + (size_t)k*nc);
        float x = ctxL[rT][k];
        a0+=bfl(w.x)*x; a1+=bfh(w.x)*x; a2+=bfl(w.y)*x; a3+=bfh(w.y)*x;
      }
      op[0]=a0; op[1]=a1; op[2]=a2; op[3]=a3;
    }
    __syncthreads();
    // gates -> h_{j+1}
    {
      int tok = stokI[rT][j];
      const float* tg = tab_dec + (size_t)tok*H3;
      float rg = sigm(tg[cT]     + gicL[rT][cT]     + ghL[rT][cT]     + b_r);
      float zg = sigm(tg[cT+256] + gicL[rT][cT+256] + ghL[rT][cT+256] + b_z);
      float ng = tanh1(tg[cT+512] + gicL[rT][cT+512] + rg*(ghL[rT][cT+512] + b_n));
      hL[rT][cT] = (1.f-zg)*ng + zg*hL[rT][cT];
    }
    __syncthreads();
    // phase B: q_{j+1}, gh_{j+1}, ph (from new h)
    PHASE_B
    __syncthreads();
    // pre = tab_pre + pc + ph
    {
      int tok = stokI[rT][j];
      preL[rT][cT] = tab_pre[(size_t)tok*HH + cT] + pcL[rT][cT] + phL[rT][cT];
    }
    __syncthreads();
    // logits = pre @ wgenT (N=64 padded)
    if (tid<128){
      int r = tid>>6, n = tid&63;
      const u16* wb = wgenT + n;
      float acc = 0.f;
      #pragma unroll 8
      for (int k=0;k<256;k++) acc += b2f(wb[k*64]) * preL[r][k];
      lgtL[r][n] = acc;
    }
    __syncthreads();
    // nll: wave 0 -> row 0, wave 1 -> row 1
    if (wv<2){
      float lg = (lane<VV)? lgtL[wv][lane] : NEGF;
      float m = lg;
      #pragma unroll
      for (int off=32; off; off>>=1) m = fmaxf(m, __shfl_xor(m,off));
      float pe = (lane<VV)? __expf(lg-m) : 0.f;
      float ss = pe;
      #pragma unroll
      for (int off=32; off; off>>=1) ss += __shfl_xor(ss,off);
      int ty = stokI[wv][j+1];
      if (lane==0 && ty!=0) nlacc += m + __logf(ss) - lgtL[wv][ty];
    }
    __syncthreads();
  }
  if (tid==0)  nred[0] = nlacc;
  if (tid==64) nred[1] = nlacc;
  __syncthreads();
  if (tid==0) nll_part[bx] = nred[0] + nred[1];
}

__global__ __launch_bounds__(256) void k_loss(const float* __restrict__ nll_part,
                                              float* __restrict__ out)
{
  __shared__ float sm[256];
  int tid=threadIdx.x;
  sm[tid] = nll_part[tid];
  __syncthreads();
  for (int off=128; off; off>>=1){
    if (tid<off) sm[tid]+=sm[tid+off];
    __syncthreads();
  }
  if (tid==0) out[0]=sm[0];
}

extern "C" void kernel_launch(void* const* d_in, const int* in_sizes, int n_in,
                              void* d_out, int out_size, void* d_ws, size_t ws_size,
                              hipStream_t stream)
{
  const int*   input    = (const int*)  d_in[0];
  const float* src_emb  = (const float*)d_in[1];
  const float* trg_emb  = (const float*)d_in[2];
  const float* eWih_f   = (const float*)d_in[3];
  const float* eWhh_f   = (const float*)d_in[4];
  const float* ebih_f   = (const float*)d_in[5];
  const float* ebhh_f   = (const float*)d_in[6];
  const float* eWih_b   = (const float*)d_in[7];
  const float* eWhh_b   = (const float*)d_in[8];
  const float* ebih_b   = (const float*)d_in[9];
  const float* ebhh_b   = (const float*)d_in[10];
  const float* bridge_W = (const float*)d_in[11];
  const float* bridge_b = (const float*)d_in[12];
  const float* attn_Wk  = (const float*)d_in[13];
  const float* attn_Wq  = (const float*)d_in[14];
  const float* attn_We  = (const float*)d_in[15];
  const float* dec_Wih  = (const float*)d_in[16];
  const float* dec_Whh  = (const float*)d_in[17];
  const float* dec_bih  = (const float*)d_in[18];
  const float* dec_bhh  = (const float*)d_in[19];
  const float* pre_W    = (const float*)d_in[20];
  const float* gen_W    = (const float*)d_in[21];

  float* F = (float*)d_ws;
  size_t o=0;
  float* tab_gi_f = F+o; o+=(size_t)VV*H3;
  float* tab_gi_b = F+o; o+=(size_t)VV*H3;
  float* tab_dec  = F+o; o+=(size_t)VV*H3;
  float* tab_pre  = F+o; o+=(size_t)VV*HH;
  float* h_f      = F+o; o+=(size_t)BB*HH;
  float* h_b      = F+o; o+=(size_t)BB*HH;
  float* hst      = F+o; o+=(size_t)BB*HH;
  float* nll_part = F+o; o+=(size_t)256;
  u16* U = (u16*)(F+o);
  size_t uo=0;
  u16* enc_out = U+uo; uo+=(size_t)BB*TT*H2;
  u16* pk      = U+uo; uo+=(size_t)BB*TT*HH;
  u16* wb_ehh_f= U+uo; uo+=(size_t)H3*HH;
  u16* wb_ehh_b= U+uo; uo+=(size_t)H3*HH;
  u16* wb_wk   = U+uo; uo+=(size_t)HH*H2;
  u16* wqT     = U+uo; uo+=(size_t)HH*HH;
  u16* whhT    = U+uo; uo+=(size_t)HH*H3;
  u16* wihcT   = U+uo; uo+=(size_t)H2*H3;
  u16* wpcT    = U+uo; uo+=(size_t)H2*HH;
  u16* wphT    = U+uo; uo+=(size_t)HH*HH;
  u16* wgenT   = U+uo; uo+=(size_t)HH*64;

  dim3 blk(256,1,1);
  k_tables<<<dim3(VV,10),blk,0,stream>>>(src_emb,trg_emb,eWih_f,ebih_f,eWih_b,ebih_b,
                                         dec_Wih,dec_bih,pre_W,
                                         tab_gi_f,tab_gi_b,tab_dec,tab_pre);
  k_cvt_all<<<dim3(5440),blk,0,stream>>>(eWhh_f,eWhh_b,attn_Wk,attn_Wq,dec_Whh,dec_Wih,pre_W,gen_W,
                                         wb_ehh_f,wb_ehh_b,wb_wk,wqT,whhT,wihcT,wpcT,wphT,wgenT);
  k_enc_all<<<dim3(32),dim3(512),0,stream>>>(input,wb_ehh_f,wb_ehh_b,ebhh_f,ebhh_b,
                                             tab_gi_f,tab_gi_b,h_f,h_b,enc_out);
  k_pk<<<dim3(1024),blk,0,stream>>>(enc_out,wb_wk,pk);
  k_bridge<<<dim3(4,8),blk,0,stream>>>(h_f,h_b,bridge_W,bridge_b,hst);
  k_dec2<<<dim3(256),dim3(512),0,stream>>>(input,hst,tab_dec,tab_pre,dec_bhh,attn_We,
                                           wqT,whhT,wihcT,wpcT,wphT,wgenT,
                                           pk,enc_out,nll_part);
  k_loss<<<dim3(1),blk,0,stream>>>(nll_part,(float*)d_out);
}

// Round 11
// 11862.528 us; speedup vs baseline: 3.3496x; 3.3496x over previous
//
#include <hip/hip_runtime.h>

#define BB 512
#define TT 128
#define EE 512
#define HH 256
#define VV 39
#define H3 768
#define H2 512
#define TM1 127
#define NEGF (-3.402823466e38f)

typedef unsigned short u16;
typedef unsigned int u32;
typedef __attribute__((ext_vector_type(8))) short s16x8;
typedef __attribute__((ext_vector_type(4))) float f32x4;
typedef __attribute__((ext_vector_type(4))) unsigned int u32x4;

__device__ __forceinline__ float b2f(u16 u){ u32 x=((u32)u)<<16; return __uint_as_float(x); }
__device__ __forceinline__ u16 f2b(float f){ u32 x=__float_as_uint(f); u32 r=(x+0x7fffu+((x>>16)&1u))>>16; return (u16)r; }
__device__ __forceinline__ float sigm(float x){ return 1.f/(1.f+__expf(-x)); }
__device__ __forceinline__ float tanh1(float x){ float t=__expf(2.f*x); return 1.f-2.f/(t+1.f); }

#define MFMA __builtin_amdgcn_mfma_f32_16x16x32_bf16

// ---------------------------------------------------------------------------
__global__ __launch_bounds__(256) void k_tables(
    const float* __restrict__ src_emb, const float* __restrict__ trg_emb,
    const float* __restrict__ Wih_f, const float* __restrict__ bih_f,
    const float* __restrict__ Wih_b, const float* __restrict__ bih_b,
    const float* __restrict__ dec_Wih, const float* __restrict__ dec_bih,
    const float* __restrict__ pre_W,
    float* __restrict__ tab_gi_f, float* __restrict__ tab_gi_b,
    float* __restrict__ tab_dec, float* __restrict__ tab_pre)
{
  int v = blockIdx.x;
  int y = blockIdx.y;
  int tid = threadIdx.x;
  if (y < 9){
    int seg = y/3, part = y%3;
    int n = part*256 + tid;
    const float* emb; const float* W; const float* bias; float* out; int ldw;
    if (seg==0){ emb=src_emb; W=Wih_f; bias=bih_f; out=tab_gi_f; ldw=EE; }
    else if (seg==1){ emb=src_emb; W=Wih_b; bias=bih_b; out=tab_gi_b; ldw=EE; }
    else { emb=trg_emb; W=dec_Wih; bias=dec_bih; out=tab_dec; ldw=EE+H2; }
    float acc = bias[n];
    const float* er = emb + (size_t)v*EE;
    const float* wr = W + (size_t)n*ldw;
    for (int k=0;k<EE;k++) acc += er[k]*wr[k];
    out[(size_t)v*H3 + n] = acc;
  } else {
    int n = tid;
    float acc = 0.f;
    const float* er = trg_emb + (size_t)v*EE;
    const float* wr = pre_W + (size_t)n*1280;
    for (int k=0;k<EE;k++) acc += er[k]*wr[k];
    tab_pre[(size_t)v*HH + n] = acc;
  }
}

// All fp32->bf16 weight conversions. grid(5440).
__global__ __launch_bounds__(256) void k_cvt_all(
    const float* __restrict__ eWhh_f, const float* __restrict__ eWhh_b,
    const float* __restrict__ dWhh, const float* __restrict__ dWih,
    const float* __restrict__ Wk, const float* __restrict__ Wq,
    const float* __restrict__ preW, const float* __restrict__ genW,
    u16* __restrict__ o1, u16* __restrict__ o2, u16* __restrict__ o3,
    u16* __restrict__ o4, u16* __restrict__ o5, u16* __restrict__ o6,
    u16* __restrict__ o7, u16* __restrict__ o8, u16* __restrict__ o9)
{
  int idx = blockIdx.x*256 + threadIdx.x;
  const float* src; u16* dst; int cols, ld, off, rel;
  if      (idx <  196608){ rel=idx;          src=eWhh_f; dst=o1; cols=256; ld=256;  off=0;   }
  else if (idx <  393216){ rel=idx-196608;   src=eWhh_b; dst=o2; cols=256; ld=256;  off=0;   }
  else if (idx <  589824){ rel=idx-393216;   src=dWhh;   dst=o3; cols=256; ld=256;  off=0;   }
  else if (idx <  983040){ rel=idx-589824;   src=dWih;   dst=o4; cols=512; ld=1024; off=512; }
  else if (idx < 1114112){ rel=idx-983040;   src=Wk;     dst=o5; cols=512; ld=512;  off=0;   }
  else if (idx < 1179648){ rel=idx-1114112;  src=Wq;     dst=o6; cols=256; ld=256;  off=0;   }
  else if (idx < 1245184){ rel=idx-1179648;  src=preW;   dst=o7; cols=256; ld=1280; off=512; }
  else if (idx < 1376256){ rel=idx-1245184;  src=preW;   dst=o8; cols=512; ld=1280; off=768; }
  else if (idx < 1392640){
    rel=idx-1376256; int r=rel>>8, c2=rel&255;
    o9[rel] = (r<VV)? f2b(genW[(size_t)r*HH + c2]) : (u16)0;
    return;
  }
  else return;
  int r = rel/cols, c2 = rel - r*cols;
  dst[rel] = f2b(src[(size_t)r*ld + off + c2]);
}

// ---------------------------------------------------------------------------
// WHOLE encoder in one kernel, zero grid barriers. grid(32), block 512.
__global__ __launch_bounds__(512) void k_enc_all(const int* __restrict__ input,
    const u16* __restrict__ wb_f, const u16* __restrict__ wb_b,
    const float* __restrict__ bhh_f, const float* __restrict__ bhh_b,
    const float* __restrict__ tab_f, const float* __restrict__ tab_b,
    float* __restrict__ h_f, float* __restrict__ h_b, u16* __restrict__ enc_out)
{
  __shared__ float gh[32][772];
  __shared__ u16 hs[32][264];
  int bx = blockIdx.x;
  int dirb = bx>>4, mt = bx&15;
  int m0 = mt*32;
  int tid = threadIdx.x;
  const float* tab = dirb? tab_b : tab_f;
  const float* bhh = dirb? bhh_b : bhh_f;
  const u16* Wb = dirb? wb_b : wb_f;
  int c = tid & 255, rh = tid>>8;
  float b_r=bhh[c], b_z=bhh[c+256], b_n=bhh[c+512];
  float hreg[16];
  #pragma unroll
  for (int r=0;r<16;r++) hreg[r]=0.f;
  int wv = tid>>6, lane = tid&63, l15 = lane&15, kg=(lane>>4)*8;
  int n0w = wv*96;
  float* hOut = dirb? h_b : h_f;

  for (int s=1; s<=TT; s++){
    int tcol = dirb? (TT-s) : (s-1);
    #pragma unroll
    for (int r=0;r<16;r++){
      int row = rh*16 + r;
      int b = m0 + row;
      int tok = input[b*TT + tcol];
      const float* tg = tab + (size_t)tok*H3;
      float g0=0.f, g1=0.f, g2=0.f;
      if (s>1){ g0=gh[row][c]; g1=gh[row][c+256]; g2=gh[row][c+512]; }
      float rg = sigm(tg[c]     + g0 + b_r);
      float zg = sigm(tg[c+256] + g1 + b_z);
      float ng = tanh1(tg[c+512] + rg*(g2 + b_n));
      float hv = (1.f-zg)*ng + zg*hreg[r];
      hreg[r] = hv;
      u16 hb = f2b(hv);
      hs[row][c] = hb;
      enc_out[((size_t)b*TT + tcol)*H2 + (size_t)dirb*HH + c] = hb;
    }
    if (s==TT){
      #pragma unroll
      for (int r=0;r<16;r++)
        hOut[(size_t)(m0+rh*16+r)*HH + c] = hreg[r];
      break;
    }
    __syncthreads();
    f32x4 acc[2][6];
    #pragma unroll
    for (int rt=0;rt<2;rt++)
      #pragma unroll
      for (int nt=0;nt<6;nt++) acc[rt][nt]=(f32x4){0.f,0.f,0.f,0.f};
    const u16* ar0 = &hs[l15][0];
    const u16* ar1 = &hs[16+l15][0];
    for (int ko=0;ko<256;ko+=32){
      s16x8 a0 = *(const s16x8*)(ar0 + ko + kg);
      s16x8 a1 = *(const s16x8*)(ar1 + ko + kg);
      #pragma unroll
      for (int nt=0;nt<6;nt++){
        s16x8 bf = *(const s16x8*)(Wb + (size_t)(n0w+nt*16+l15)*HH + ko + kg);
        acc[0][nt] = MFMA(a0, bf, acc[0][nt], 0,0,0);
        acc[1][nt] = MFMA(a1, bf, acc[1][nt], 0,0,0);
      }
    }
    int q4 = (lane>>4)*4;
    #pragma unroll
    for (int rt=0;rt<2;rt++)
      #pragma unroll
      for (int nt=0;nt<6;nt++){
        int col = n0w + nt*16 + l15;
        #pragma unroll
        for (int j=0;j<4;j++)
          gh[rt*16 + q4 + j][col] = acc[rt][nt][j];
      }
    __syncthreads();
  }
}

// proj_key = enc_out @ Wk^T : MFMA. grid(1024), block 256.
__global__ __launch_bounds__(256) void k_pk(const u16* __restrict__ enc_out,
    const u16* __restrict__ wbk, u16* __restrict__ pk)
{
  int m0 = blockIdx.x*64;
  int tid = threadIdx.x, wv = tid>>6, lane = tid&63;
  int l15 = lane&15, kg = (lane>>4)*8;
  int n0 = wv*64;
  f32x4 acc[4][4];
  #pragma unroll
  for (int rt=0;rt<4;rt++)
    #pragma unroll
    for (int nt=0;nt<4;nt++) acc[rt][nt] = (f32x4){0.f,0.f,0.f,0.f};
  for (int ko=0; ko<512; ko+=32){
    s16x8 a[4], b[4];
    #pragma unroll
    for (int rt=0;rt<4;rt++) a[rt] = *(const s16x8*)(enc_out + (size_t)(m0+rt*16+l15)*H2 + ko + kg);
    #pragma unroll
    for (int nt=0;nt<4;nt++) b[nt] = *(const s16x8*)(wbk + (size_t)(n0+nt*16+l15)*H2 + ko + kg);
    #pragma unroll
    for (int rt=0;rt<4;rt++)
      #pragma unroll
      for (int nt=0;nt<4;nt++)
        acc[rt][nt] = MFMA(a[rt], b[nt], acc[rt][nt], 0,0,0);
  }
  #pragma unroll
  for (int rt=0;rt<4;rt++){
    int rbase = m0 + rt*16 + (lane>>4)*4;
    #pragma unroll
    for (int nt=0;nt<4;nt++){
      int col = n0 + nt*16 + l15;
      #pragma unroll
      for (int j=0;j<4;j++)
        pk[(size_t)(rbase+j)*HH + col] = f2b(acc[rt][nt][j]);
    }
  }
}

// hidden = tanh([h_f|h_b] @ bridge_W^T + b) -> hst. grid (4,8).
__global__ __launch_bounds__(256) void k_bridge(const float* __restrict__ h_f,
    const float* __restrict__ h_b, const float* __restrict__ bw,
    const float* __restrict__ bb, float* __restrict__ hst)
{
  __shared__ float As[32][68];
  __shared__ float Ws[32][68];
  int n0=blockIdx.x*64, m0=blockIdx.y*64, tid=threadIdx.x;
  int ar=tid>>2, ak=(tid&3)*8;
  int rt=tid>>4, ct=tid&15;
  float acc[4][4];
  #pragma unroll
  for (int j=0;j<4;j++){
    #pragma unroll
    for (int l=0;l<4;l++) acc[j][l]=0.f;
  }
  for (int ko=0;ko<512;ko+=32){
    int k0=ko+ak;
    const float* asrc = (k0<256)? (h_f + (size_t)(m0+ar)*HH + k0)
                                : (h_b + (size_t)(m0+ar)*HH + (k0-256));
    float4 a0=*(const float4*)asrc, a1=*(const float4*)(asrc+4);
    const float* wsrc = bw + (size_t)(n0+ar)*H2 + k0;
    float4 w0=*(const float4*)wsrc, w1=*(const float4*)(wsrc+4);
    __syncthreads();
    As[ak+0][ar]=a0.x; As[ak+1][ar]=a0.y; As[ak+2][ar]=a0.z; As[ak+3][ar]=a0.w;
    As[ak+4][ar]=a1.x; As[ak+5][ar]=a1.y; As[ak+6][ar]=a1.z; As[ak+7][ar]=a1.w;
    Ws[ak+0][ar]=w0.x; Ws[ak+1][ar]=w0.y; Ws[ak+2][ar]=w0.z; Ws[ak+3][ar]=w0.w;
    Ws[ak+4][ar]=w1.x; Ws[ak+5][ar]=w1.y; Ws[ak+6][ar]=w1.z; Ws[ak+7][ar]=w1.w;
    __syncthreads();
    #pragma unroll
    for (int kk=0;kk<32;kk++){
      float4 a=*(const float4*)&As[kk][rt*4];
      float4 w=*(const float4*)&Ws[kk][ct*4];
      float a4[4]={a.x,a.y,a.z,a.w};
      float w4[4]={w.x,w.y,w.z,w.w};
      #pragma unroll
      for (int j=0;j<4;j++){
        #pragma unroll
        for (int l=0;l<4;l++) acc[j][l]+=a4[j]*w4[l];
      }
    }
  }
  #pragma unroll
  for (int j=0;j<4;j++){
    int row=m0+rt*4+j;
    #pragma unroll
    for (int l=0;l<4;l++){
      int col=n0+ct*4+l;
      hst[(size_t)row*HH+col]=tanh1(acc[j][l]+bb[col]);
    }
  }
}

// Bootstrap: q0 = h0@Wq, gh0 = h0@Whh, zero nll. grid(32), block 256.
__global__ __launch_bounds__(256) void k_boot(
    const float* __restrict__ hst, const u16* __restrict__ whh,
    const u16* __restrict__ wq, float* __restrict__ ghg,
    float* __restrict__ qg, float* __restrict__ nll)
{
  __shared__ u16 hsb[16][264];
  int bx=blockIdx.x, tid=threadIdx.x;
  int wv=tid>>6, lane=tid&63, l15=lane&15, kg=(lane>>4)*8;
  int b0=bx*16;
  {
    int c=tid;
    for (int r=0;r<16;r++) hsb[r][c] = f2b(hst[(size_t)(b0+r)*HH + c]);
  }
  if (tid<16) nll[b0+tid] = 0.f;
  __syncthreads();
  int rr = (lane>>4)*4;
  for (int nt=0;nt<12;nt++){
    int n0 = wv*192 + nt*16;
    f32x4 acc = (f32x4){0.f,0.f,0.f,0.f};
    for (int ko=0;ko<256;ko+=32){
      s16x8 a = *(const s16x8*)&hsb[l15][ko+kg];
      s16x8 bf = *(const s16x8*)(whh + (size_t)(n0+l15)*HH + ko + kg);
      acc = MFMA(a, bf, acc, 0,0,0);
    }
    #pragma unroll
    for (int jr=0;jr<4;jr++)
      ghg[(size_t)(b0+rr+jr)*H3 + n0 + l15] = acc[jr];
  }
  #pragma unroll
  for (int nt=0;nt<4;nt++){
    int n0 = wv*64 + nt*16;
    f32x4 acc = (f32x4){0.f,0.f,0.f,0.f};
    for (int ko=0;ko<256;ko+=32){
      s16x8 a = *(const s16x8*)&hsb[l15][ko+kg];
      s16x8 bf = *(const s16x8*)(wq + (size_t)(n0+l15)*HH + ko + kg);
      acc = MFMA(a, bf, acc, 0,0,0);
    }
    #pragma unroll
    for (int jr=0;jr<4;jr++)
      qg[(size_t)(b0+rr+jr)*HH + n0 + l15] = acc[jr];
  }
}

// ---------------------------------------------------------------------------
// Attention step: one block per row, 512 thr (8 waves), 2 blocks/CU.
// e-phase loads all 8 pk fragments up front (max MLP); ctx in 4-deep groups.
__global__ __launch_bounds__(512,4) void k_attn(
    const int* __restrict__ input, const float* __restrict__ qg,
    const u16* __restrict__ pk, const u16* __restrict__ enc_out,
    const float* __restrict__ We, u16* __restrict__ ctx_bf)
{
  __shared__ float aL[TT];
  __shared__ int stok[TT];
  __shared__ float part[8][512];
  int b = blockIdx.x, tid = threadIdx.x;
  int wv = tid>>6, lane = tid&63, l32 = lane&31;
  if (tid < TT) stok[tid] = input[b*TT + tid];
  const float* qb = qg + (size_t)b*HH + l32*8;
  float4 q0 = *(const float4*)qb;
  float4 q1 = *(const float4*)(qb+4);
  float4 w0 = *(const float4*)(We + l32*8);
  float4 w1 = *(const float4*)(We + l32*8 + 4);
  const u16* pkb = pk + (size_t)b*TT*HH + l32*8;
  __syncthreads();
  // e: wave wv owns t in [16wv,16wv+16); (lane>>5) splits pairs; 8 its.
  {
    s16x8 kv[8];
    #pragma unroll
    for (int it=0; it<8; it++){
      int t = wv*16 + it*2 + (lane>>5);
      kv[it] = *(const s16x8*)(pkb + (size_t)t*HH);
    }
    #pragma unroll
    for (int it=0; it<8; it++){
      int t = wv*16 + it*2 + (lane>>5);
      s16x8 k8 = kv[it];
      float s = tanh1(q0.x + b2f((u16)k8[0]))*w0.x
              + tanh1(q0.y + b2f((u16)k8[1]))*w0.y
              + tanh1(q0.z + b2f((u16)k8[2]))*w0.z
              + tanh1(q0.w + b2f((u16)k8[3]))*w0.w
              + tanh1(q1.x + b2f((u16)k8[4]))*w1.x
              + tanh1(q1.y + b2f((u16)k8[5]))*w1.y
              + tanh1(q1.z + b2f((u16)k8[6]))*w1.z
              + tanh1(q1.w + b2f((u16)k8[7]))*w1.w;
      #pragma unroll
      for (int off=16; off; off>>=1) s += __shfl_xor(s, off);
      if (l32==0) aL[t] = stok[t] ? s : NEGF;
    }
  }
  __syncthreads();
  if (wv==0){
    float v0 = aL[lane], v1 = aL[64+lane];
    float m = fmaxf(v0,v1);
    #pragma unroll
    for (int off=32; off; off>>=1) m = fmaxf(m, __shfl_xor(m,off));
    float p0 = __expf(v0-m), p1 = __expf(v1-m);
    float s = p0+p1;
    #pragma unroll
    for (int off=32; off; off>>=1) s += __shfl_xor(s,off);
    float inv = 1.f/s;
    aL[lane] = p0*inv; aL[64+lane] = p1*inv;
  }
  __syncthreads();
  // ctx: wave wv owns t in [16wv,16wv+16); lane owns dims [8lane,+8); 4-deep.
  float cacc[8];
  #pragma unroll
  for (int e=0;e<8;e++) cacc[e]=0.f;
  const u16* eb = enc_out + (size_t)b*TT*H2 + lane*8;
  int t0 = wv*16;
  #pragma unroll
  for (int g=0; g<4; g++){
    s16x8 e0 = *(const s16x8*)(eb + (size_t)(t0+g*4+0)*H2);
    s16x8 e1 = *(const s16x8*)(eb + (size_t)(t0+g*4+1)*H2);
    s16x8 e2 = *(const s16x8*)(eb + (size_t)(t0+g*4+2)*H2);
    s16x8 e3 = *(const s16x8*)(eb + (size_t)(t0+g*4+3)*H2);
    float a0=aL[t0+g*4], a1=aL[t0+g*4+1], a2=aL[t0+g*4+2], a3=aL[t0+g*4+3];
    #pragma unroll
    for (int e=0;e<8;e++)
      cacc[e] += a0*b2f((u16)e0[e]) + a1*b2f((u16)e1[e])
               + a2*b2f((u16)e2[e]) + a3*b2f((u16)e3[e]);
  }
  #pragma unroll
  for (int e=0;e<8;e++) part[wv][lane*8+e] = cacc[e];
  __syncthreads();
  float s2 = 0.f;
  #pragma unroll
  for (int w=0;w<8;w++) s2 += part[w][tid];
  ctx_bf[(size_t)b*H2 + tid] = f2b(s2);
}

// ---------------------------------------------------------------------------
// Decoder batch step: 32 blocks x 16 rows, 512 thr (8 waves). MFMA GEMMs.
__global__ __launch_bounds__(512) void k_dstep(int j,
    const int* __restrict__ input,
    const float* __restrict__ tab_dec, const float* __restrict__ tab_pre,
    const float* __restrict__ bhh,
    const u16* __restrict__ whh, const u16* __restrict__ wih,
    const u16* __restrict__ wq, const u16* __restrict__ wph,
    const u16* __restrict__ wpc, const u16* __restrict__ wgen,
    const u16* __restrict__ ctx_bf, float* __restrict__ hst,
    float* __restrict__ qg, float* __restrict__ ghg,
    float* __restrict__ nll)
{
  __shared__ u16 cs[16][520];
  __shared__ u16 hsb[16][264];
  __shared__ u16 gicL[16][776];
  __shared__ u16 pcL[16][264];
  __shared__ u16 preb[16][264];
  __shared__ float lgt[16][64];
  __shared__ int stokL[16];
  int bx = blockIdx.x, tid = threadIdx.x;
  int wv = tid>>6, lane = tid&63, l15 = lane&15, kg = (lane>>4)*8;
  int b0 = bx*16;
  int rr = (lane>>4)*4;
  float b_r, b_z, b_n;
  { int c=tid&255; b_r=bhh[c]; b_z=bhh[c+256]; b_n=bhh[c+512]; }

  for (int idx = tid; idx < 1024; idx += 512){
    int r = idx>>6, cc = (idx&63)*8;
    *(u32x4*)&cs[r][cc] = *(const u32x4*)(ctx_bf + (size_t)(b0+r)*H2 + cc);
  }
  if (tid < 16) stokL[tid] = input[(b0+tid)*TT + j];
  __syncthreads();

  // gic = ctx @ Wih_ctx^T (N=768, K=512): 6 ntiles/wave
  #pragma unroll 2
  for (int nt=0;nt<6;nt++){
    int n0 = wv*96 + nt*16;
    f32x4 acc = (f32x4){0.f,0.f,0.f,0.f};
    for (int ko=0;ko<512;ko+=32){
      s16x8 a = *(const s16x8*)&cs[l15][ko+kg];
      s16x8 bf = *(const s16x8*)(wih + (size_t)(n0+l15)*H2 + ko + kg);
      acc = MFMA(a,bf,acc,0,0,0);
    }
    #pragma unroll
    for (int jr=0;jr<4;jr++) gicL[rr+jr][n0+l15] = f2b(acc[jr]);
  }
  // pc = ctx @ wpre_ctx^T (N=256): 2 ntiles/wave
  #pragma unroll
  for (int nt=0;nt<2;nt++){
    int n0 = wv*32 + nt*16;
    f32x4 acc = (f32x4){0.f,0.f,0.f,0.f};
    for (int ko=0;ko<512;ko+=32){
      s16x8 a = *(const s16x8*)&cs[l15][ko+kg];
      s16x8 bf = *(const s16x8*)(wpc + (size_t)(n0+l15)*H2 + ko + kg);
      acc = MFMA(a,bf,acc,0,0,0);
    }
    #pragma unroll
    for (int jr=0;jr<4;jr++) pcL[rr+jr][n0+l15] = f2b(acc[jr]);
  }
  __syncthreads();

  // gates -> h_{j+1}: c=tid&255, rows (tid>>8)*8..+8
  {
    int c = tid&255, rh = tid>>8;
    for (int r=rh*8; r<rh*8+8; r++){
      int bb = b0+r;
      const float* tg = tab_dec + (size_t)stokL[r]*H3;
      const float* gr = ghg + (size_t)bb*H3;
      float rg = sigm(tg[c]     + b2f(gicL[r][c])     + gr[c]     + b_r);
      float zg = sigm(tg[c+256] + b2f(gicL[r][c+256]) + gr[c+256] + b_z);
      float ng = tanh1(tg[c+512] + b2f(gicL[r][c+512]) + rg*(gr[c+512] + b_n));
      float hv = (1.f-zg)*ng + zg*hst[(size_t)bb*HH + c];
      hst[(size_t)bb*HH + c] = hv;
      hsb[r][c] = f2b(hv);
    }
  }
  __syncthreads();

  // gh_{j+1} = h @ Whh^T (N=768)
  #pragma unroll 2
  for (int nt=0;nt<6;nt++){
    int n0 = wv*96 + nt*16;
    f32x4 acc = (f32x4){0.f,0.f,0.f,0.f};
    for (int ko=0;ko<256;ko+=32){
      s16x8 a = *(const s16x8*)&hsb[l15][ko+kg];
      s16x8 bf = *(const s16x8*)(whh + (size_t)(n0+l15)*HH + ko + kg);
      acc = MFMA(a,bf,acc,0,0,0);
    }
    #pragma unroll
    for (int jr=0;jr<4;jr++)
      ghg[(size_t)(b0+rr+jr)*H3 + n0 + l15] = acc[jr];
  }
  // q_{j+1} = h @ Wq^T (N=256)
  #pragma unroll
  for (int nt=0;nt<2;nt++){
    int n0 = wv*32 + nt*16;
    f32x4 acc = (f32x4){0.f,0.f,0.f,0.f};
    for (int ko=0;ko<256;ko+=32){
      s16x8 a = *(const s16x8*)&hsb[l15][ko+kg];
      s16x8 bf = *(const s16x8*)(wq + (size_t)(n0+l15)*HH + ko + kg);
      acc = MFMA(a,bf,acc,0,0,0);
    }
    #pragma unroll
    for (int jr=0;jr<4;jr++)
      qg[(size_t)(b0+rr+jr)*HH + n0 + l15] = acc[jr];
  }
  // pre = tab_pre + pc + h @ wpre_h^T (N=256)
  #pragma unroll
  for (int nt=0;nt<2;nt++){
    int n0 = wv*32 + nt*16;
    f32x4 acc = (f32x4){0.f,0.f,0.f,0.f};
    for (int ko=0;ko<256;ko+=32){
      s16x8 a = *(const s16x8*)&hsb[l15][ko+kg];
      s16x8 bf = *(const s16x8*)(wph + (size_t)(n0+l15)*HH + ko + kg);
      acc = MFMA(a,bf,acc,0,0,0);
    }
    #pragma unroll
    for (int jr=0;jr<4;jr++){
      int r = rr+jr;
      float pv = acc[jr] + b2f(pcL[r][n0+l15]) + tab_pre[(size_t)stokL[r]*HH + n0 + l15];
      preb[r][n0+l15] = f2b(pv);
    }
  }
  __syncthreads();

  // logits = pre @ genW^T (N=64): waves 0..3
  if (wv<4){
    int n0 = wv*16;
    f32x4 acc = (f32x4){0.f,0.f,0.f,0.f};
    for (int ko=0;ko<256;ko+=32){
      s16x8 a = *(const s16x8*)&preb[l15][ko+kg];
      s16x8 bf = *(const s16x8*)(wgen + (size_t)(n0+l15)*HH + ko + kg);
      acc = MFMA(a,bf,acc,0,0,0);
    }
    #pragma unroll
    for (int jr=0;jr<4;jr++) lgt[rr+jr][n0+l15] = acc[jr];
  }
  __syncthreads();

  // nll: 16-lane group per row (waves 0..3)
  {
    int r = wv*4 + (lane>>4);
    if (r < 16){
      float v0 = lgt[r][l15];
      float v1 = lgt[r][l15+16];
      float v2 = (l15<7)? lgt[r][l15+32] : NEGF;
      float m = fmaxf(fmaxf(v0,v1),v2);
      #pragma unroll
      for (int off=8; off; off>>=1) m = fmaxf(m, __shfl_xor(m,off));
      float pe = __expf(v0-m) + __expf(v1-m) + ((l15<7)? __expf(v2-m) : 0.f);
      #pragma unroll
      for (int off=8; off; off>>=1) pe += __shfl_xor(pe,off);
      if (l15==0){
        int ty = input[(b0+r)*TT + j+1];
        if (ty != 0) nll[b0+r] += m + __logf(pe) - lgt[r][ty];
      }
    }
  }
}

__global__ __launch_bounds__(256) void k_loss(const float* __restrict__ nll,
                                              float* __restrict__ out)
{
  __shared__ float sm[256];
  int tid=threadIdx.x;
  float s = nll[tid] + nll[tid+256];
  sm[tid]=s; __syncthreads();
  for (int off=128; off; off>>=1){
    if (tid<off) sm[tid]+=sm[tid+off];
    __syncthreads();
  }
  if (tid==0) out[0]=sm[0];
}

extern "C" void kernel_launch(void* const* d_in, const int* in_sizes, int n_in,
                              void* d_out, int out_size, void* d_ws, size_t ws_size,
                              hipStream_t stream)
{
  const int*   input    = (const int*)  d_in[0];
  const float* src_emb  = (const float*)d_in[1];
  const float* trg_emb  = (const float*)d_in[2];
  const float* eWih_f   = (const float*)d_in[3];
  const float* eWhh_f   = (const float*)d_in[4];
  const float* ebih_f   = (const float*)d_in[5];
  const float* ebhh_f   = (const float*)d_in[6];
  const float* eWih_b   = (const float*)d_in[7];
  const float* eWhh_b   = (const float*)d_in[8];
  const float* ebih_b   = (const float*)d_in[9];
  const float* ebhh_b   = (const float*)d_in[10];
  const float* bridge_W = (const float*)d_in[11];
  const float* bridge_b = (const float*)d_in[12];
  const float* attn_Wk  = (const float*)d_in[13];
  const float* attn_Wq  = (const float*)d_in[14];
  const float* attn_We  = (const float*)d_in[15];
  const float* dec_Wih  = (const float*)d_in[16];
  const float* dec_Whh  = (const float*)d_in[17];
  const float* dec_bih  = (const float*)d_in[18];
  const float* dec_bhh  = (const float*)d_in[19];
  const float* pre_W    = (const float*)d_in[20];
  const float* gen_W    = (const float*)d_in[21];

  float* F = (float*)d_ws;
  size_t o=0;
  float* tab_gi_f = F+o; o+=(size_t)VV*H3;
  float* tab_gi_b = F+o; o+=(size_t)VV*H3;
  float* tab_dec  = F+o; o+=(size_t)VV*H3;
  float* tab_pre  = F+o; o+=(size_t)VV*HH;
  float* h_f      = F+o; o+=(size_t)BB*HH;
  float* h_b      = F+o; o+=(size_t)BB*HH;
  float* hst      = F+o; o+=(size_t)BB*HH;
  float* qg       = F+o; o+=(size_t)BB*HH;
  float* ghg      = F+o; o+=(size_t)BB*H3;
  float* nll      = F+o; o+=(size_t)BB;
  u16* U = (u16*)(F+o);
  size_t uo=0;
  u16* enc_out = U+uo; uo+=(size_t)BB*TT*H2;
  u16* pk      = U+uo; uo+=(size_t)BB*TT*HH;
  u16* ctx_bf  = U+uo; uo+=(size_t)BB*H2;
  u16* wb_ehh_f= U+uo; uo+=(size_t)H3*HH;
  u16* wb_ehh_b= U+uo; uo+=(size_t)H3*HH;
  u16* wb_dhh  = U+uo; uo+=(size_t)H3*HH;
  u16* wb_dih  = U+uo; uo+=(size_t)H3*H2;
  u16* wb_wk   = U+uo; uo+=(size_t)HH*H2;
  u16* wb_wq   = U+uo; uo+=(size_t)HH*HH;
  u16* wb_ph   = U+uo; uo+=(size_t)HH*HH;
  u16* wb_pc   = U+uo; uo+=(size_t)HH*H2;
  u16* wb_gen  = U+uo; uo+=(size_t)64*HH;

  dim3 blk(256,1,1);
  k_tables<<<dim3(VV,10),blk,0,stream>>>(src_emb,trg_emb,eWih_f,ebih_f,eWih_b,ebih_b,
                                         dec_Wih,dec_bih,pre_W,
                                         tab_gi_f,tab_gi_b,tab_dec,tab_pre);
  k_cvt_all<<<dim3(5440),blk,0,stream>>>(eWhh_f,eWhh_b,dec_Whh,dec_Wih,attn_Wk,attn_Wq,pre_W,gen_W,
                                         wb_ehh_f,wb_ehh_b,wb_dhh,wb_dih,wb_wk,wb_wq,
                                         wb_ph,wb_pc,wb_gen);
  k_enc_all<<<dim3(32),dim3(512),0,stream>>>(input,wb_ehh_f,wb_ehh_b,ebhh_f,ebhh_b,
                                             tab_gi_f,tab_gi_b,h_f,h_b,enc_out);
  k_pk<<<dim3(1024),blk,0,stream>>>(enc_out,wb_wk,pk);
  k_bridge<<<dim3(4,8),blk,0,stream>>>(h_f,h_b,bridge_W,bridge_b,hst);
  k_boot<<<dim3(32),blk,0,stream>>>(hst,wb_dhh,wb_wq,ghg,qg,nll);

  for (int j=0;j<TM1;j++){
    k_attn<<<dim3(BB),dim3(512),0,stream>>>(input,qg,pk,enc_out,attn_We,ctx_bf);
    k_dstep<<<dim3(32),dim3(512),0,stream>>>(j,input,tab_dec,tab_pre,dec_bhh,
                                             wb_dhh,wb_dih,wb_wq,wb_ph,wb_pc,wb_gen,
                                             ctx_bf,hst,qg,ghg,nll);
  }
  k_loss<<<dim3(1),blk,0,stream>>>(nll,(float*)d_out);
}

// Round 12
// 11731.628 us; speedup vs baseline: 3.3870x; 1.0112x over previous
//
#include <hip/hip_runtime.h>

#define BB 512
#define TT 128
#define EE 512
#define HH 256
#define VV 39
#define H3 768
#define H2 512
#define TM1 127
#define NEGF (-3.402823466e38f)

typedef unsigned short u16;
typedef unsigned int u32;
typedef __attribute__((ext_vector_type(8))) short s16x8;
typedef __attribute__((ext_vector_type(4))) float f32x4;
typedef __attribute__((ext_vector_type(4))) unsigned int u32x4;

__device__ __forceinline__ float b2f(u16 u){ u32 x=((u32)u)<<16; return __uint_as_float(x); }
__device__ __forceinline__ u16 f2b(float f){ u32 x=__float_as_uint(f); u32 r=(x+0x7fffu+((x>>16)&1u))>>16; return (u16)r; }
__device__ __forceinline__ float sigm(float x){ return 1.f/(1.f+__expf(-x)); }
__device__ __forceinline__ float tanh1(float x){ float t=__expf(2.f*x); return 1.f-2.f/(t+1.f); }

#define MFMA __builtin_amdgcn_mfma_f32_16x16x32_bf16

__device__ __forceinline__ u32 aload(const u32* p){
  return __hip_atomic_load(p, __ATOMIC_RELAXED, __HIP_MEMORY_SCOPE_AGENT);
}
__device__ __forceinline__ void astore(u32* p, u32 v){
  __hip_atomic_store(p, v, __ATOMIC_RELAXED, __HIP_MEMORY_SCOPE_AGENT);
}
#define QF(g) ((g)*16)

// ---------------------------------------------------------------------------
__global__ __launch_bounds__(256) void k_tables(
    const float* __restrict__ src_emb, const float* __restrict__ trg_emb,
    const float* __restrict__ Wih_f, const float* __restrict__ bih_f,
    const float* __restrict__ Wih_b, const float* __restrict__ bih_b,
    const float* __restrict__ dec_Wih, const float* __restrict__ dec_bih,
    const float* __restrict__ pre_W,
    float* __restrict__ tab_gi_f, float* __restrict__ tab_gi_b,
    float* __restrict__ tab_dec, float* __restrict__ tab_pre)
{
  int v = blockIdx.x;
  int y = blockIdx.y;
  int tid = threadIdx.x;
  if (y < 9){
    int seg = y/3, part = y%3;
    int n = part*256 + tid;
    const float* emb; const float* W; const float* bias; float* out; int ldw;
    if (seg==0){ emb=src_emb; W=Wih_f; bias=bih_f; out=tab_gi_f; ldw=EE; }
    else if (seg==1){ emb=src_emb; W=Wih_b; bias=bih_b; out=tab_gi_b; ldw=EE; }
    else { emb=trg_emb; W=dec_Wih; bias=dec_bih; out=tab_dec; ldw=EE+H2; }
    float acc = bias[n];
    const float* er = emb + (size_t)v*EE;
    const float* wr = W + (size_t)n*ldw;
    for (int k=0;k<EE;k++) acc += er[k]*wr[k];
    out[(size_t)v*H3 + n] = acc;
  } else {
    int n = tid;
    float acc = 0.f;
    const float* er = trg_emb + (size_t)v*EE;
    const float* wr = pre_W + (size_t)n*1280;
    for (int k=0;k<EE;k++) acc += er[k]*wr[k];
    tab_pre[(size_t)v*HH + n] = acc;
  }
}

// All fp32->bf16 weight conversions. grid(5440).
__global__ __launch_bounds__(256) void k_cvt_all(
    const float* __restrict__ eWhh_f, const float* __restrict__ eWhh_b,
    const float* __restrict__ dWhh, const float* __restrict__ dWih,
    const float* __restrict__ Wk, const float* __restrict__ Wq,
    const float* __restrict__ preW, const float* __restrict__ genW,
    u16* __restrict__ o1, u16* __restrict__ o2, u16* __restrict__ o3,
    u16* __restrict__ o4, u16* __restrict__ o5, u16* __restrict__ o6,
    u16* __restrict__ o7, u16* __restrict__ o8, u16* __restrict__ o9)
{
  int idx = blockIdx.x*256 + threadIdx.x;
  const float* src; u16* dst; int cols, ld, off, rel;
  if      (idx <  196608){ rel=idx;          src=eWhh_f; dst=o1; cols=256; ld=256;  off=0;   }
  else if (idx <  393216){ rel=idx-196608;   src=eWhh_b; dst=o2; cols=256; ld=256;  off=0;   }
  else if (idx <  589824){ rel=idx-393216;   src=dWhh;   dst=o3; cols=256; ld=256;  off=0;   }
  else if (idx <  983040){ rel=idx-589824;   src=dWih;   dst=o4; cols=512; ld=1024; off=512; }
  else if (idx < 1114112){ rel=idx-983040;   src=Wk;     dst=o5; cols=512; ld=512;  off=0;   }
  else if (idx < 1179648){ rel=idx-1114112;  src=Wq;     dst=o6; cols=256; ld=256;  off=0;   }
  else if (idx < 1245184){ rel=idx-1179648;  src=preW;   dst=o7; cols=256; ld=1280; off=512; }
  else if (idx < 1376256){ rel=idx-1245184;  src=preW;   dst=o8; cols=512; ld=1280; off=768; }
  else if (idx < 1392640){
    rel=idx-1376256; int r=rel>>8, c2=rel&255;
    o9[rel] = (r<VV)? f2b(genW[(size_t)r*HH + c2]) : (u16)0;
    return;
  }
  else return;
  int r = rel/cols, c2 = rel - r*cols;
  dst[rel] = f2b(src[(size_t)r*ld + off + c2]);
}

// ---------------------------------------------------------------------------
// WHOLE encoder in one kernel, zero grid barriers. grid(32), block 512.
__global__ __launch_bounds__(512) void k_enc_all(const int* __restrict__ input,
    const u16* __restrict__ wb_f, const u16* __restrict__ wb_b,
    const float* __restrict__ bhh_f, const float* __restrict__ bhh_b,
    const float* __restrict__ tab_f, const float* __restrict__ tab_b,
    float* __restrict__ h_f, float* __restrict__ h_b, u16* __restrict__ enc_out)
{
  __shared__ float gh[32][772];
  __shared__ u16 hs[32][264];
  int bx = blockIdx.x;
  int dirb = bx>>4, mt = bx&15;
  int m0 = mt*32;
  int tid = threadIdx.x;
  const float* tab = dirb? tab_b : tab_f;
  const float* bhh = dirb? bhh_b : bhh_f;
  const u16* Wb = dirb? wb_b : wb_f;
  int c = tid & 255, rh = tid>>8;
  float b_r=bhh[c], b_z=bhh[c+256], b_n=bhh[c+512];
  float hreg[16];
  #pragma unroll
  for (int r=0;r<16;r++) hreg[r]=0.f;
  int wv = tid>>6, lane = tid&63, l15 = lane&15, kg=(lane>>4)*8;
  int n0w = wv*96;
  float* hOut = dirb? h_b : h_f;

  for (int s=1; s<=TT; s++){
    int tcol = dirb? (TT-s) : (s-1);
    #pragma unroll
    for (int r=0;r<16;r++){
      int row = rh*16 + r;
      int b = m0 + row;
      int tok = input[b*TT + tcol];
      const float* tg = tab + (size_t)tok*H3;
      float g0=0.f, g1=0.f, g2=0.f;
      if (s>1){ g0=gh[row][c]; g1=gh[row][c+256]; g2=gh[row][c+512]; }
      float rg = sigm(tg[c]     + g0 + b_r);
      float zg = sigm(tg[c+256] + g1 + b_z);
      float ng = tanh1(tg[c+512] + rg*(g2 + b_n));
      float hv = (1.f-zg)*ng + zg*hreg[r];
      hreg[r] = hv;
      u16 hb = f2b(hv);
      hs[row][c] = hb;
      enc_out[((size_t)b*TT + tcol)*H2 + (size_t)dirb*HH + c] = hb;
    }
    if (s==TT){
      #pragma unroll
      for (int r=0;r<16;r++)
        hOut[(size_t)(m0+rh*16+r)*HH + c] = hreg[r];
      break;
    }
    __syncthreads();
    f32x4 acc[2][6];
    #pragma unroll
    for (int rt=0;rt<2;rt++)
      #pragma unroll
      for (int nt=0;nt<6;nt++) acc[rt][nt]=(f32x4){0.f,0.f,0.f,0.f};
    const u16* ar0 = &hs[l15][0];
    const u16* ar1 = &hs[16+l15][0];
    for (int ko=0;ko<256;ko+=32){
      s16x8 a0 = *(const s16x8*)(ar0 + ko + kg);
      s16x8 a1 = *(const s16x8*)(ar1 + ko + kg);
      #pragma unroll
      for (int nt=0;nt<6;nt++){
        s16x8 bf = *(const s16x8*)(Wb + (size_t)(n0w+nt*16+l15)*HH + ko + kg);
        acc[0][nt] = MFMA(a0, bf, acc[0][nt], 0,0,0);
        acc[1][nt] = MFMA(a1, bf, acc[1][nt], 0,0,0);
      }
    }
    int q4 = (lane>>4)*4;
    #pragma unroll
    for (int rt=0;rt<2;rt++)
      #pragma unroll
      for (int nt=0;nt<6;nt++){
        int col = n0w + nt*16 + l15;
        #pragma unroll
        for (int j=0;j<4;j++)
          gh[rt*16 + q4 + j][col] = acc[rt][nt][j];
      }
    __syncthreads();
  }
}

// proj_key = enc_out @ Wk^T : MFMA. grid(1024), block 256.
__global__ __launch_bounds__(256) void k_pk(const u16* __restrict__ enc_out,
    const u16* __restrict__ wbk, u16* __restrict__ pk)
{
  int m0 = blockIdx.x*64;
  int tid = threadIdx.x, wv = tid>>6, lane = tid&63;
  int l15 = lane&15, kg = (lane>>4)*8;
  int n0 = wv*64;
  f32x4 acc[4][4];
  #pragma unroll
  for (int rt=0;rt<4;rt++)
    #pragma unroll
    for (int nt=0;nt<4;nt++) acc[rt][nt] = (f32x4){0.f,0.f,0.f,0.f};
  for (int ko=0; ko<512; ko+=32){
    s16x8 a[4], b[4];
    #pragma unroll
    for (int rt=0;rt<4;rt++) a[rt] = *(const s16x8*)(enc_out + (size_t)(m0+rt*16+l15)*H2 + ko + kg);
    #pragma unroll
    for (int nt=0;nt<4;nt++) b[nt] = *(const s16x8*)(wbk + (size_t)(n0+nt*16+l15)*H2 + ko + kg);
    #pragma unroll
    for (int rt=0;rt<4;rt++)
      #pragma unroll
      for (int nt=0;nt<4;nt++)
        acc[rt][nt] = MFMA(a[rt], b[nt], acc[rt][nt], 0,0,0);
  }
  #pragma unroll
  for (int rt=0;rt<4;rt++){
    int rbase = m0 + rt*16 + (lane>>4)*4;
    #pragma unroll
    for (int nt=0;nt<4;nt++){
      int col = n0 + nt*16 + l15;
      #pragma unroll
      for (int j=0;j<4;j++)
        pk[(size_t)(rbase+j)*HH + col] = f2b(acc[rt][nt][j]);
    }
  }
}

// hidden = tanh([h_f|h_b] @ bridge_W^T + b) -> hst. grid (4,8).
__global__ __launch_bounds__(256) void k_bridge(const float* __restrict__ h_f,
    const float* __restrict__ h_b, const float* __restrict__ bw,
    const float* __restrict__ bb, float* __restrict__ hst)
{
  __shared__ float As[32][68];
  __shared__ float Ws[32][68];
  int n0=blockIdx.x*64, m0=blockIdx.y*64, tid=threadIdx.x;
  int ar=tid>>2, ak=(tid&3)*8;
  int rt=tid>>4, ct=tid&15;
  float acc[4][4];
  #pragma unroll
  for (int j=0;j<4;j++){
    #pragma unroll
    for (int l=0;l<4;l++) acc[j][l]=0.f;
  }
  for (int ko=0;ko<512;ko+=32){
    int k0=ko+ak;
    const float* asrc = (k0<256)? (h_f + (size_t)(m0+ar)*HH + k0)
                                : (h_b + (size_t)(m0+ar)*HH + (k0-256));
    float4 a0=*(const float4*)asrc, a1=*(const float4*)(asrc+4);
    const float* wsrc = bw + (size_t)(n0+ar)*H2 + k0;
    float4 w0=*(const float4*)wsrc, w1=*(const float4*)(wsrc+4);
    __syncthreads();
    As[ak+0][ar]=a0.x; As[ak+1][ar]=a0.y; As[ak+2][ar]=a0.z; As[ak+3][ar]=a0.w;
    As[ak+4][ar]=a1.x; As[ak+5][ar]=a1.y; As[ak+6][ar]=a1.z; As[ak+7][ar]=a1.w;
    Ws[ak+0][ar]=w0.x; Ws[ak+1][ar]=w0.y; Ws[ak+2][ar]=w0.z; Ws[ak+3][ar]=w0.w;
    Ws[ak+4][ar]=w1.x; Ws[ak+5][ar]=w1.y; Ws[ak+6][ar]=w1.z; Ws[ak+7][ar]=w1.w;
    __syncthreads();
    #pragma unroll
    for (int kk=0;kk<32;kk++){
      float4 a=*(const float4*)&As[kk][rt*4];
      float4 w=*(const float4*)&Ws[kk][ct*4];
      float a4[4]={a.x,a.y,a.z,a.w};
      float w4[4]={w.x,w.y,w.z,w.w};
      #pragma unroll
      for (int j=0;j<4;j++){
        #pragma unroll
        for (int l=0;l<4;l++) acc[j][l]+=a4[j]*w4[l];
      }
    }
  }
  #pragma unroll
  for (int j=0;j<4;j++){
    int row=m0+rt*4+j;
    #pragma unroll
    for (int l=0;l<4;l++){
      int col=n0+ct*4+l;
      hst[(size_t)row*HH+col]=tanh1(acc[j][l]+bb[col]);
    }
  }
}

// Bootstrap: q0 = h0@Wq, gh0 = h0@Whh, zero nll. grid(32), block 256.
__global__ __launch_bounds__(256) void k_boot(
    const float* __restrict__ hst, const u16* __restrict__ whh,
    const u16* __restrict__ wq, float* __restrict__ ghg,
    float* __restrict__ qg, float* __restrict__ nll)
{
  __shared__ u16 hsb[16][264];
  int bx=blockIdx.x, tid=threadIdx.x;
  int wv=tid>>6, lane=tid&63, l15=lane&15, kg=(lane>>4)*8;
  int b0=bx*16;
  {
    int c=tid;
    for (int r=0;r<16;r++) hsb[r][c] = f2b(hst[(size_t)(b0+r)*HH + c]);
  }
  if (tid<16) nll[b0+tid] = 0.f;
  __syncthreads();
  int rr = (lane>>4)*4;
  for (int nt=0;nt<12;nt++){
    int n0 = wv*192 + nt*16;
    f32x4 acc = (f32x4){0.f,0.f,0.f,0.f};
    for (int ko=0;ko<256;ko+=32){
      s16x8 a = *(const s16x8*)&hsb[l15][ko+kg];
      s16x8 bf = *(const s16x8*)(whh + (size_t)(n0+l15)*HH + ko + kg);
      acc = MFMA(a, bf, acc, 0,0,0);
    }
    #pragma unroll
    for (int jr=0;jr<4;jr++)
      ghg[(size_t)(b0+rr+jr)*H3 + n0 + l15] = acc[jr];
  }
  #pragma unroll
  for (int nt=0;nt<4;nt++){
    int n0 = wv*64 + nt*16;
    f32x4 acc = (f32x4){0.f,0.f,0.f,0.f};
    for (int ko=0;ko<256;ko+=32){
      s16x8 a = *(const s16x8*)&hsb[l15][ko+kg];
      s16x8 bf = *(const s16x8*)(wq + (size_t)(n0+l15)*HH + ko + kg);
      acc = MFMA(a, bf, acc, 0,0,0);
    }
    #pragma unroll
    for (int jr=0;jr<4;jr++)
      qg[(size_t)(b0+rr+jr)*HH + n0 + l15] = acc[jr];
  }
}

// ---------------------------------------------------------------------------
// ONE kernel per decoder step L (L=0..127). grid(512) x 512 thr (2 blocks/CU).
// Blocks 0..31: GEMM for step s=L-1 (ctx from prev launch, plain loads);
// publishes q_L via agent atomics + flag; then attention for row bx.
// Blocks 32..511: attention row bx (pk preloaded before flag wait).
__global__ __launch_bounds__(512,4) void k_step(int L,
    const int* __restrict__ input,
    const float* __restrict__ tab_dec, const float* __restrict__ tab_pre,
    const float* __restrict__ bhh, const float* __restrict__ We,
    const u16* __restrict__ whh, const u16* __restrict__ wih,
    const u16* __restrict__ wq, const u16* __restrict__ wph,
    const u16* __restrict__ wpc, const u16* __restrict__ wgen,
    const u16* __restrict__ pk, const u16* __restrict__ enc_out,
    float* __restrict__ hst, u32* __restrict__ qgu, float* __restrict__ ghg,
    u16* __restrict__ ctxW, const u16* __restrict__ ctxR,
    float* __restrict__ nll, u32* __restrict__ fl)
{
  __shared__ __align__(16) char smem[71040];
  // gemm views
  u16 (*cs)[520]   = (u16(*)[520])smem;
  u16 (*hsb)[264]  = (u16(*)[264])(smem+16640);
  u16 (*gicL)[776] = (u16(*)[776])(smem+25088);
  u16 (*pcL)[264]  = (u16(*)[264])(smem+49920);
  u16 (*preb)[264] = (u16(*)[264])(smem+58368);
  float (*lgt)[64] = (float(*)[64])smem;        // reuses cs region (dead)
  int* stokL       = (int*)(smem+66816);
  // attn views (used after gemm part completes)
  float* aL   = (float*)smem;                   // 128 f32
  int*   stok = (int*)(smem+512);               // 128 int
  float (*part)[512] = (float(*)[512])(smem+1024);
  float* qS   = (float*)(smem+17408);           // 256 f32

  int bx = blockIdx.x, tid = threadIdx.x;
  int wv = tid>>6, lane = tid&63, l15 = lane&15, kg = (lane>>4)*8;

  // ======== GEMM part: blocks 0..31, step s=L-1 ========
  if (bx < 32 && L > 0){
    int s = L-1;
    int b0 = bx*16;
    int rr = (lane>>4)*4;
    float b_r, b_z, b_n;
    { int c=tid&255; b_r=bhh[c]; b_z=bhh[c+256]; b_n=bhh[c+512]; }
    for (int idx = tid; idx < 1024; idx += 512){
      int r = idx>>6, cc = (idx&63)*8;
      *(u32x4*)&cs[r][cc] = *(const u32x4*)(ctxR + (size_t)(b0+r)*H2 + cc);
    }
    if (tid < 16) stokL[tid] = input[(b0+tid)*TT + s];
    __syncthreads();
    // gic = ctx @ Wih_ctx^T (N=768, K=512)
    #pragma unroll 2
    for (int nt=0;nt<6;nt++){
      int n0 = wv*96 + nt*16;
      f32x4 acc = (f32x4){0.f,0.f,0.f,0.f};
      for (int ko=0;ko<512;ko+=32){
        s16x8 a = *(const s16x8*)&cs[l15][ko+kg];
        s16x8 bf = *(const s16x8*)(wih + (size_t)(n0+l15)*H2 + ko + kg);
        acc = MFMA(a,bf,acc,0,0,0);
      }
      #pragma unroll
      for (int jr=0;jr<4;jr++) gicL[rr+jr][n0+l15] = f2b(acc[jr]);
    }
    // pc = ctx @ wpre_ctx^T (N=256)
    #pragma unroll
    for (int nt=0;nt<2;nt++){
      int n0 = wv*32 + nt*16;
      f32x4 acc = (f32x4){0.f,0.f,0.f,0.f};
      for (int ko=0;ko<512;ko+=32){
        s16x8 a = *(const s16x8*)&cs[l15][ko+kg];
        s16x8 bf = *(const s16x8*)(wpc + (size_t)(n0+l15)*H2 + ko + kg);
        acc = MFMA(a,bf,acc,0,0,0);
      }
      #pragma unroll
      for (int jr=0;jr<4;jr++) pcL[rr+jr][n0+l15] = f2b(acc[jr]);
    }
    __syncthreads();
    // gates -> h_L
    {
      int c = tid&255, rh = tid>>8;
      for (int r=rh*8; r<rh*8+8; r++){
        int bb = b0+r;
        const float* tg = tab_dec + (size_t)stokL[r]*H3;
        const float* gr = ghg + (size_t)bb*H3;
        float rg = sigm(tg[c]     + b2f(gicL[r][c])     + gr[c]     + b_r);
        float zg = sigm(tg[c+256] + b2f(gicL[r][c+256]) + gr[c+256] + b_z);
        float ng = tanh1(tg[c+512] + b2f(gicL[r][c+512]) + rg*(gr[c+512] + b_n));
        float hv = (1.f-zg)*ng + zg*hst[(size_t)bb*HH + c];
        hst[(size_t)bb*HH + c] = hv;
        hsb[r][c] = f2b(hv);
      }
    }
    __syncthreads();
    // q_L FIRST (agent stores), then publish flag
    #pragma unroll
    for (int nt=0;nt<2;nt++){
      int n0 = wv*32 + nt*16;
      f32x4 acc = (f32x4){0.f,0.f,0.f,0.f};
      for (int ko=0;ko<256;ko+=32){
        s16x8 a = *(const s16x8*)&hsb[l15][ko+kg];
        s16x8 bf = *(const s16x8*)(wq + (size_t)(n0+l15)*HH + ko + kg);
        acc = MFMA(a,bf,acc,0,0,0);
      }
      #pragma unroll
      for (int jr=0;jr<4;jr++)
        astore(qgu + (size_t)(b0+rr+jr)*HH + n0 + l15, __float_as_uint(acc[jr]));
    }
    __syncthreads();   // drains q stores (vmcnt 0) for all waves
    if (tid==0) astore(&fl[QF(bx)], (u32)L);
    // gh_L (private, plain stores)
    #pragma unroll 2
    for (int nt=0;nt<6;nt++){
      int n0 = wv*96 + nt*16;
      f32x4 acc = (f32x4){0.f,0.f,0.f,0.f};
      for (int ko=0;ko<256;ko+=32){
        s16x8 a = *(const s16x8*)&hsb[l15][ko+kg];
        s16x8 bf = *(const s16x8*)(whh + (size_t)(n0+l15)*HH + ko + kg);
        acc = MFMA(a,bf,acc,0,0,0);
      }
      #pragma unroll
      for (int jr=0;jr<4;jr++)
        ghg[(size_t)(b0+rr+jr)*H3 + n0 + l15] = acc[jr];
    }
    // pre = tab_pre + pc + h @ wpre_h^T
    #pragma unroll
    for (int nt=0;nt<2;nt++){
      int n0 = wv*32 + nt*16;
      f32x4 acc = (f32x4){0.f,0.f,0.f,0.f};
      for (int ko=0;ko<256;ko+=32){
        s16x8 a = *(const s16x8*)&hsb[l15][ko+kg];
        s16x8 bf = *(const s16x8*)(wph + (size_t)(n0+l15)*HH + ko + kg);
        acc = MFMA(a,bf,acc,0,0,0);
      }
      #pragma unroll
      for (int jr=0;jr<4;jr++){
        int r = rr+jr;
        float pv = acc[jr] + b2f(pcL[r][n0+l15]) + tab_pre[(size_t)stokL[r]*HH + n0 + l15];
        preb[r][n0+l15] = f2b(pv);
      }
    }
    __syncthreads();
    // logits (waves 0..3; lgt reuses cs region — cs dead)
    if (wv<4){
      int n0 = wv*16;
      f32x4 acc = (f32x4){0.f,0.f,0.f,0.f};
      for (int ko=0;ko<256;ko+=32){
        s16x8 a = *(const s16x8*)&preb[l15][ko+kg];
        s16x8 bf = *(const s16x8*)(wgen + (size_t)(n0+l15)*HH + ko + kg);
        acc = MFMA(a,bf,acc,0,0,0);
      }
      #pragma unroll
      for (int jr=0;jr<4;jr++) lgt[rr+jr][n0+l15] = acc[jr];
    }
    __syncthreads();
    // nll accumulate (plain RMW, own rows)
    {
      int r = wv*4 + (lane>>4);
      if (r < 16){
        float v0 = lgt[r][l15];
        float v1 = lgt[r][l15+16];
        float v2 = (l15<7)? lgt[r][l15+32] : NEGF;
        float m = fmaxf(fmaxf(v0,v1),v2);
        #pragma unroll
        for (int off=8; off; off>>=1) m = fmaxf(m, __shfl_xor(m,off));
        float pe = __expf(v0-m) + __expf(v1-m) + ((l15<7)? __expf(v2-m) : 0.f);
        #pragma unroll
        for (int off=8; off; off>>=1) pe += __shfl_xor(pe,off);
        if (l15==0){
          int ty = input[(b0+r)*TT + s+1];
          if (ty != 0) nll[b0+r] += m + __logf(pe) - lgt[r][ty];
        }
      }
    }
    __syncthreads();
  }

  // ======== Attention part: all blocks, row bx, step L ========
  if (L < TM1){
    int r2 = bx;
    int g2 = r2>>4;
    int l32 = lane&31;
    if (tid < TT) stok[tid] = input[r2*TT + tid];
    // preload full pk row into VGPRs BEFORE the flag wait (overlaps gemm)
    const u16* pkb = pk + (size_t)r2*TT*HH + l32*8;
    s16x8 kv[8];
    #pragma unroll
    for (int it=0; it<8; it++){
      int t = wv*16 + it*2 + (lane>>5);
      kv[it] = *(const s16x8*)(pkb + (size_t)t*HH);
    }
    float4 w0 = *(const float4*)(We + l32*8);
    float4 w1 = *(const float4*)(We + l32*8 + 4);
    __syncthreads();
    if (L > 0){
      if (tid==0){
        while (aload(&fl[QF(g2)]) < (u32)L) __builtin_amdgcn_s_sleep(1);
      }
      __syncthreads();
    }
    if (tid < 256) qS[tid] = __uint_as_float(aload(qgu + (size_t)r2*HH + tid));
    __syncthreads();
    float4 q0 = *(const float4*)&qS[l32*8];
    float4 q1 = *(const float4*)&qS[l32*8 + 4];
    #pragma unroll
    for (int it=0; it<8; it++){
      int t = wv*16 + it*2 + (lane>>5);
      s16x8 k8 = kv[it];
      float sE = tanh1(q0.x + b2f((u16)k8[0]))*w0.x
               + tanh1(q0.y + b2f((u16)k8[1]))*w0.y
               + tanh1(q0.z + b2f((u16)k8[2]))*w0.z
               + tanh1(q0.w + b2f((u16)k8[3]))*w0.w
               + tanh1(q1.x + b2f((u16)k8[4]))*w1.x
               + tanh1(q1.y + b2f((u16)k8[5]))*w1.y
               + tanh1(q1.z + b2f((u16)k8[6]))*w1.z
               + tanh1(q1.w + b2f((u16)k8[7]))*w1.w;
      #pragma unroll
      for (int off=16; off; off>>=1) sE += __shfl_xor(sE, off);
      if (l32==0) aL[t] = stok[t] ? sE : NEGF;
    }
    __syncthreads();
    if (wv==0){
      float v0 = aL[lane], v1 = aL[64+lane];
      float m = fmaxf(v0,v1);
      #pragma unroll
      for (int off=32; off; off>>=1) m = fmaxf(m, __shfl_xor(m,off));
      float p0 = __expf(v0-m), p1 = __expf(v1-m);
      float sS = p0+p1;
      #pragma unroll
      for (int off=32; off; off>>=1) sS += __shfl_xor(sS,off);
      float inv = 1.f/sS;
      aL[lane] = p0*inv; aL[64+lane] = p1*inv;
    }
    __syncthreads();
    float cacc[8];
    #pragma unroll
    for (int e=0;e<8;e++) cacc[e]=0.f;
    const u16* eb = enc_out + (size_t)r2*TT*H2 + lane*8;
    int t0 = wv*16;
    #pragma unroll
    for (int g=0; g<4; g++){
      s16x8 e0 = *(const s16x8*)(eb + (size_t)(t0+g*4+0)*H2);
      s16x8 e1 = *(const s16x8*)(eb + (size_t)(t0+g*4+1)*H2);
      s16x8 e2 = *(const s16x8*)(eb + (size_t)(t0+g*4+2)*H2);
      s16x8 e3 = *(const s16x8*)(eb + (size_t)(t0+g*4+3)*H2);
      float a0=aL[t0+g*4], a1=aL[t0+g*4+1], a2=aL[t0+g*4+2], a3=aL[t0+g*4+3];
      #pragma unroll
      for (int e=0;e<8;e++)
        cacc[e] += a0*b2f((u16)e0[e]) + a1*b2f((u16)e1[e])
                 + a2*b2f((u16)e2[e]) + a3*b2f((u16)e3[e]);
    }
    #pragma unroll
    for (int e=0;e<8;e++) part[wv][lane*8+e] = cacc[e];
    __syncthreads();
    float s2 = 0.f;
    #pragma unroll
    for (int w=0;w<8;w++) s2 += part[w][tid];
    ctxW[(size_t)r2*H2 + tid] = f2b(s2);   // plain store; read next launch
  }
}

__global__ __launch_bounds__(256) void k_loss(const float* __restrict__ nll,
                                              float* __restrict__ out)
{
  __shared__ float sm[256];
  int tid=threadIdx.x;
  float s = nll[tid] + nll[tid+256];
  sm[tid]=s; __syncthreads();
  for (int off=128; off; off>>=1){
    if (tid<off) sm[tid]+=sm[tid+off];
    __syncthreads();
  }
  if (tid==0) out[0]=sm[0];
}

extern "C" void kernel_launch(void* const* d_in, const int* in_sizes, int n_in,
                              void* d_out, int out_size, void* d_ws, size_t ws_size,
                              hipStream_t stream)
{
  const int*   input    = (const int*)  d_in[0];
  const float* src_emb  = (const float*)d_in[1];
  const float* trg_emb  = (const float*)d_in[2];
  const float* eWih_f   = (const float*)d_in[3];
  const float* eWhh_f   = (const float*)d_in[4];
  const float* ebih_f   = (const float*)d_in[5];
  const float* ebhh_f   = (const float*)d_in[6];
  const float* eWih_b   = (const float*)d_in[7];
  const float* eWhh_b   = (const float*)d_in[8];
  const float* ebih_b   = (const float*)d_in[9];
  const float* ebhh_b   = (const float*)d_in[10];
  const float* bridge_W = (const float*)d_in[11];
  const float* bridge_b = (const float*)d_in[12];
  const float* attn_Wk  = (const float*)d_in[13];
  const float* attn_Wq  = (const float*)d_in[14];
  const float* attn_We  = (const float*)d_in[15];
  const float* dec_Wih  = (const float*)d_in[16];
  const float* dec_Whh  = (const float*)d_in[17];
  const float* dec_bih  = (const float*)d_in[18];
  const float* dec_bhh  = (const float*)d_in[19];
  const float* pre_W    = (const float*)d_in[20];
  const float* gen_W    = (const float*)d_in[21];

  float* F = (float*)d_ws;
  size_t o=0;
  u32* fl         = (u32*)(F+o); o+=2048;
  float* tab_gi_f = F+o; o+=(size_t)VV*H3;
  float* tab_gi_b = F+o; o+=(size_t)VV*H3;
  float* tab_dec  = F+o; o+=(size_t)VV*H3;
  float* tab_pre  = F+o; o+=(size_t)VV*HH;
  float* h_f      = F+o; o+=(size_t)BB*HH;
  float* h_b      = F+o; o+=(size_t)BB*HH;
  float* hst      = F+o; o+=(size_t)BB*HH;
  float* qg       = F+o; o+=(size_t)BB*HH;
  float* ghg      = F+o; o+=(size_t)BB*H3;
  float* nll      = F+o; o+=(size_t)BB;
  u16* U = (u16*)(F+o);
  size_t uo=0;
  u16* enc_out = U+uo; uo+=(size_t)BB*TT*H2;
  u16* pk      = U+uo; uo+=(size_t)BB*TT*HH;
  u16* ctx0    = U+uo; uo+=(size_t)BB*H2;
  u16* ctx1    = U+uo; uo+=(size_t)BB*H2;
  u16* wb_ehh_f= U+uo; uo+=(size_t)H3*HH;
  u16* wb_ehh_b= U+uo; uo+=(size_t)H3*HH;
  u16* wb_dhh  = U+uo; uo+=(size_t)H3*HH;
  u16* wb_dih  = U+uo; uo+=(size_t)H3*H2;
  u16* wb_wk   = U+uo; uo+=(size_t)HH*H2;
  u16* wb_wq   = U+uo; uo+=(size_t)HH*HH;
  u16* wb_ph   = U+uo; uo+=(size_t)HH*HH;
  u16* wb_pc   = U+uo; uo+=(size_t)HH*H2;
  u16* wb_gen  = U+uo; uo+=(size_t)64*HH;

  dim3 blk(256,1,1);
  k_tables<<<dim3(VV,10),blk,0,stream>>>(src_emb,trg_emb,eWih_f,ebih_f,eWih_b,ebih_b,
                                         dec_Wih,dec_bih,pre_W,
                                         tab_gi_f,tab_gi_b,tab_dec,tab_pre);
  k_cvt_all<<<dim3(5440),blk,0,stream>>>(eWhh_f,eWhh_b,dec_Whh,dec_Wih,attn_Wk,attn_Wq,pre_W,gen_W,
                                         wb_ehh_f,wb_ehh_b,wb_dhh,wb_dih,wb_wk,wb_wq,
                                         wb_ph,wb_pc,wb_gen);
  k_enc_all<<<dim3(32),dim3(512),0,stream>>>(input,wb_ehh_f,wb_ehh_b,ebhh_f,ebhh_b,
                                             tab_gi_f,tab_gi_b,h_f,h_b,enc_out);
  k_pk<<<dim3(1024),blk,0,stream>>>(enc_out,wb_wk,pk);
  k_bridge<<<dim3(4,8),blk,0,stream>>>(h_f,h_b,bridge_W,bridge_b,hst);
  k_boot<<<dim3(32),blk,0,stream>>>(hst,wb_dhh,wb_wq,ghg,qg,nll);
  hipMemsetAsync(fl, 0, 8192, stream);

  for (int L=0; L<=TM1; L++){
    u16* cw = (L&1)? ctx1 : ctx0;
    u16* cr = (L&1)? ctx0 : ctx1;
    k_step<<<dim3(512),dim3(512),0,stream>>>(L,input,tab_dec,tab_pre,dec_bhh,attn_We,
                                             wb_dhh,wb_dih,wb_wq,wb_ph,wb_pc,wb_gen,
                                             pk,enc_out,hst,(u32*)qg,ghg,
                                             cw,cr,nll,fl);
  }
  k_loss<<<dim3(1),blk,0,stream>>>(nll,(float*)d_out);
}

// Round 13
// 9235.725 us; speedup vs baseline: 4.3023x; 1.2702x over previous
//
#include <hip/hip_runtime.h>

#define BB 512
#define TT 128
#define EE 512
#define HH 256
#define VV 39
#define H3 768
#define H2 512
#define TM1 127
#define NEGF (-3.402823466e38f)

typedef unsigned short u16;
typedef unsigned int u32;
typedef __attribute__((ext_vector_type(8))) short s16x8;
typedef __attribute__((ext_vector_type(4))) float f32x4;
typedef __attribute__((ext_vector_type(2))) unsigned int u32x2;
typedef __attribute__((ext_vector_type(4))) unsigned int u32x4;

__device__ __forceinline__ float b2f(u16 u){ u32 x=((u32)u)<<16; return __uint_as_float(x); }
__device__ __forceinline__ u16 f2b(float f){ u32 x=__float_as_uint(f); u32 r=(x+0x7fffu+((x>>16)&1u))>>16; return (u16)r; }
__device__ __forceinline__ float sigm(float x){ return 1.f/(1.f+__expf(-x)); }
__device__ __forceinline__ float tanh1(float x){ float t=__expf(2.f*x); return 1.f-2.f/(t+1.f); }
__device__ __forceinline__ float bfl(u32 u){ return __uint_as_float(u<<16); }
__device__ __forceinline__ float bfh(u32 u){ return __uint_as_float(u & 0xffff0000u); }

#define MFMA __builtin_amdgcn_mfma_f32_16x16x32_bf16

__device__ __forceinline__ u32 aload(const u32* p){
  return __hip_atomic_load(p, __ATOMIC_RELAXED, __HIP_MEMORY_SCOPE_AGENT);
}
__device__ __forceinline__ void astore(u32* p, u32 v){
  __hip_atomic_store(p, v, __ATOMIC_RELAXED, __HIP_MEMORY_SCOPE_AGENT);
}
#define QF(g) ((g)*16)

// ---------------------------------------------------------------------------
__global__ __launch_bounds__(256) void k_tables(
    const float* __restrict__ src_emb, const float* __restrict__ trg_emb,
    const float* __restrict__ Wih_f, const float* __restrict__ bih_f,
    const float* __restrict__ Wih_b, const float* __restrict__ bih_b,
    const float* __restrict__ dec_Wih, const float* __restrict__ dec_bih,
    const float* __restrict__ pre_W,
    float* __restrict__ tab_gi_f, float* __restrict__ tab_gi_b,
    float* __restrict__ tab_dec, float* __restrict__ tab_pre)
{
  int v = blockIdx.x;
  int y = blockIdx.y;
  int tid = threadIdx.x;
  if (y < 9){
    int seg = y/3, part = y%3;
    int n = part*256 + tid;
    const float* emb; const float* W; const float* bias; float* out; int ldw;
    if (seg==0){ emb=src_emb; W=Wih_f; bias=bih_f; out=tab_gi_f; ldw=EE; }
    else if (seg==1){ emb=src_emb; W=Wih_b; bias=bih_b; out=tab_gi_b; ldw=EE; }
    else { emb=trg_emb; W=dec_Wih; bias=dec_bih; out=tab_dec; ldw=EE+H2; }
    float acc = bias[n];
    const float* er = emb + (size_t)v*EE;
    const float* wr = W + (size_t)n*ldw;
    for (int k=0;k<EE;k++) acc += er[k]*wr[k];
    out[(size_t)v*H3 + n] = acc;
  } else {
    int n = tid;
    float acc = 0.f;
    const float* er = trg_emb + (size_t)v*EE;
    const float* wr = pre_W + (size_t)n*1280;
    for (int k=0;k<EE;k++) acc += er[k]*wr[k];
    tab_pre[(size_t)v*HH + n] = acc;
  }
}

// All fp32->bf16 weight conversions. grid(5440).
__global__ __launch_bounds__(256) void k_cvt_all(
    const float* __restrict__ eWhh_f, const float* __restrict__ eWhh_b,
    const float* __restrict__ dWhh, const float* __restrict__ dWih,
    const float* __restrict__ Wk, const float* __restrict__ Wq,
    const float* __restrict__ preW, const float* __restrict__ genW,
    u16* __restrict__ o1, u16* __restrict__ o2, u16* __restrict__ o3,
    u16* __restrict__ o4, u16* __restrict__ o5, u16* __restrict__ o6,
    u16* __restrict__ o7, u16* __restrict__ o8, u16* __restrict__ o9)
{
  int idx = blockIdx.x*256 + threadIdx.x;
  const float* src; u16* dst; int cols, ld, off, rel;
  if      (idx <  196608){ rel=idx;          src=eWhh_f; dst=o1; cols=256; ld=256;  off=0;   }
  else if (idx <  393216){ rel=idx-196608;   src=eWhh_b; dst=o2; cols=256; ld=256;  off=0;   }
  else if (idx <  589824){ rel=idx-393216;   src=dWhh;   dst=o3; cols=256; ld=256;  off=0;   }
  else if (idx <  983040){ rel=idx-589824;   src=dWih;   dst=o4; cols=512; ld=1024; off=512; }
  else if (idx < 1114112){ rel=idx-983040;   src=Wk;     dst=o5; cols=512; ld=512;  off=0;   }
  else if (idx < 1179648){ rel=idx-1114112;  src=Wq;     dst=o6; cols=256; ld=256;  off=0;   }
  else if (idx < 1245184){ rel=idx-1179648;  src=preW;   dst=o7; cols=256; ld=1280; off=512; }
  else if (idx < 1376256){ rel=idx-1245184;  src=preW;   dst=o8; cols=512; ld=1280; off=768; }
  else if (idx < 1392640){
    rel=idx-1376256; int r=rel>>8, c2=rel&255;
    o9[rel] = (r<VV)? f2b(genW[(size_t)r*HH + c2]) : (u16)0;
    return;
  }
  else return;
  int r = rel/cols, c2 = rel - r*cols;
  dst[rel] = f2b(src[(size_t)r*ld + off + c2]);
}

// ---------------------------------------------------------------------------
// WHOLE encoder in one kernel; phase-B B-fragment double-buffer prefetch.
__global__ __launch_bounds__(512) void k_enc_all(const int* __restrict__ input,
    const u16* __restrict__ wb_f, const u16* __restrict__ wb_b,
    const float* __restrict__ bhh_f, const float* __restrict__ bhh_b,
    const float* __restrict__ tab_f, const float* __restrict__ tab_b,
    float* __restrict__ h_f, float* __restrict__ h_b, u16* __restrict__ enc_out)
{
  __shared__ float gh[32][772];
  __shared__ u16 hs[32][264];
  int bx = blockIdx.x;
  int dirb = bx>>4, mt = bx&15;
  int m0 = mt*32;
  int tid = threadIdx.x;
  const float* tab = dirb? tab_b : tab_f;
  const float* bhh = dirb? bhh_b : bhh_f;
  const u16* Wb = dirb? wb_b : wb_f;
  int c = tid & 255, rh = tid>>8;
  float b_r=bhh[c], b_z=bhh[c+256], b_n=bhh[c+512];
  float hreg[16];
  #pragma unroll
  for (int r=0;r<16;r++) hreg[r]=0.f;
  int wv = tid>>6, lane = tid&63, l15 = lane&15, kg=(lane>>4)*8;
  int n0w = wv*96;
  float* hOut = dirb? h_b : h_f;

  for (int s=1; s<=TT; s++){
    int tcol = dirb? (TT-s) : (s-1);
    #pragma unroll
    for (int r=0;r<16;r++){
      int row = rh*16 + r;
      int b = m0 + row;
      int tok = input[b*TT + tcol];
      const float* tg = tab + (size_t)tok*H3;
      float g0=0.f, g1=0.f, g2=0.f;
      if (s>1){ g0=gh[row][c]; g1=gh[row][c+256]; g2=gh[row][c+512]; }
      float rg = sigm(tg[c]     + g0 + b_r);
      float zg = sigm(tg[c+256] + g1 + b_z);
      float ng = tanh1(tg[c+512] + rg*(g2 + b_n));
      float hv = (1.f-zg)*ng + zg*hreg[r];
      hreg[r] = hv;
      u16 hb = f2b(hv);
      hs[row][c] = hb;
      enc_out[((size_t)b*TT + tcol)*H2 + (size_t)dirb*HH + c] = hb;
    }
    if (s==TT){
      #pragma unroll
      for (int r=0;r<16;r++)
        hOut[(size_t)(m0+rh*16+r)*HH + c] = hreg[r];
      break;
    }
    __syncthreads();
    f32x4 acc[2][6];
    #pragma unroll
    for (int rt=0;rt<2;rt++)
      #pragma unroll
      for (int nt=0;nt<6;nt++) acc[rt][nt]=(f32x4){0.f,0.f,0.f,0.f};
    const u16* ar0 = &hs[l15][0];
    const u16* ar1 = &hs[16+l15][0];
    s16x8 bcur[6], bnext[6];
    #pragma unroll
    for (int nt=0;nt<6;nt++)
      bcur[nt] = *(const s16x8*)(Wb + (size_t)(n0w+nt*16+l15)*HH + kg);
    #pragma unroll
    for (int ko=0;ko<256;ko+=32){
      if (ko<224){
        #pragma unroll
        for (int nt=0;nt<6;nt++)
          bnext[nt] = *(const s16x8*)(Wb + (size_t)(n0w+nt*16+l15)*HH + ko+32 + kg);
      }
      s16x8 a0 = *(const s16x8*)(ar0 + ko + kg);
      s16x8 a1 = *(const s16x8*)(ar1 + ko + kg);
      #pragma unroll
      for (int nt=0;nt<6;nt++){
        acc[0][nt] = MFMA(a0, bcur[nt], acc[0][nt], 0,0,0);
        acc[1][nt] = MFMA(a1, bcur[nt], acc[1][nt], 0,0,0);
      }
      #pragma unroll
      for (int nt=0;nt<6;nt++) bcur[nt]=bnext[nt];
    }
    int q4 = (lane>>4)*4;
    #pragma unroll
    for (int rt=0;rt<2;rt++)
      #pragma unroll
      for (int nt=0;nt<6;nt++){
        int col = n0w + nt*16 + l15;
        #pragma unroll
        for (int j=0;j<4;j++)
          gh[rt*16 + q4 + j][col] = acc[rt][nt][j];
      }
    __syncthreads();
  }
}

// out[m][n] = enc[m] . W[n]  (K=512). W row-major [nTot][512].
// grid (1024, nTot/256), block 256.
__global__ __launch_bounds__(256) void k_proj(const u16* __restrict__ enc,
    const u16* __restrict__ W, u16* __restrict__ out, int nTot)
{
  int m0 = blockIdx.x*64;
  int tid = threadIdx.x, wv = tid>>6, lane = tid&63;
  int l15 = lane&15, kg = (lane>>4)*8;
  int n0 = blockIdx.y*256 + wv*64;
  f32x4 acc[4][4];
  #pragma unroll
  for (int rt=0;rt<4;rt++)
    #pragma unroll
    for (int nt=0;nt<4;nt++) acc[rt][nt] = (f32x4){0.f,0.f,0.f,0.f};
  for (int ko=0; ko<512; ko+=32){
    s16x8 a[4], b[4];
    #pragma unroll
    for (int rt=0;rt<4;rt++) a[rt] = *(const s16x8*)(enc + (size_t)(m0+rt*16+l15)*H2 + ko + kg);
    #pragma unroll
    for (int nt=0;nt<4;nt++) b[nt] = *(const s16x8*)(W + (size_t)(n0+nt*16+l15)*H2 + ko + kg);
    #pragma unroll
    for (int rt=0;rt<4;rt++)
      #pragma unroll
      for (int nt=0;nt<4;nt++)
        acc[rt][nt] = MFMA(a[rt], b[nt], acc[rt][nt], 0,0,0);
  }
  #pragma unroll
  for (int rt=0;rt<4;rt++){
    int rbase = m0 + rt*16 + (lane>>4)*4;
    #pragma unroll
    for (int nt=0;nt<4;nt++){
      int col = n0 + nt*16 + l15;
      #pragma unroll
      for (int j=0;j<4;j++)
        out[(size_t)(rbase+j)*nTot + col] = f2b(acc[rt][nt][j]);
    }
  }
}

// hidden = tanh([h_f|h_b] @ bridge_W^T + b) -> hst. grid (4,8).
__global__ __launch_bounds__(256) void k_bridge(const float* __restrict__ h_f,
    const float* __restrict__ h_b, const float* __restrict__ bw,
    const float* __restrict__ bb, float* __restrict__ hst)
{
  __shared__ float As[32][68];
  __shared__ float Ws[32][68];
  int n0=blockIdx.x*64, m0=blockIdx.y*64, tid=threadIdx.x;
  int ar=tid>>2, ak=(tid&3)*8;
  int rt=tid>>4, ct=tid&15;
  float acc[4][4];
  #pragma unroll
  for (int j=0;j<4;j++){
    #pragma unroll
    for (int l=0;l<4;l++) acc[j][l]=0.f;
  }
  for (int ko=0;ko<512;ko+=32){
    int k0=ko+ak;
    const float* asrc = (k0<256)? (h_f + (size_t)(m0+ar)*HH + k0)
                                : (h_b + (size_t)(m0+ar)*HH + (k0-256));
    float4 a0=*(const float4*)asrc, a1=*(const float4*)(asrc+4);
    const float* wsrc = bw + (size_t)(n0+ar)*H2 + k0;
    float4 w0=*(const float4*)wsrc, w1=*(const float4*)(wsrc+4);
    __syncthreads();
    As[ak+0][ar]=a0.x; As[ak+1][ar]=a0.y; As[ak+2][ar]=a0.z; As[ak+3][ar]=a0.w;
    As[ak+4][ar]=a1.x; As[ak+5][ar]=a1.y; As[ak+6][ar]=a1.z; As[ak+7][ar]=a1.w;
    Ws[ak+0][ar]=w0.x; Ws[ak+1][ar]=w0.y; Ws[ak+2][ar]=w0.z; Ws[ak+3][ar]=w0.w;
    Ws[ak+4][ar]=w1.x; Ws[ak+5][ar]=w1.y; Ws[ak+6][ar]=w1.z; Ws[ak+7][ar]=w1.w;
    __syncthreads();
    #pragma unroll
    for (int kk=0;kk<32;kk++){
      float4 a=*(const float4*)&As[kk][rt*4];
      float4 w=*(const float4*)&Ws[kk][ct*4];
      float a4[4]={a.x,a.y,a.z,a.w};
      float w4[4]={w.x,w.y,w.z,w.w};
      #pragma unroll
      for (int j=0;j<4;j++){
        #pragma unroll
        for (int l=0;l<4;l++) acc[j][l]+=a4[j]*w4[l];
      }
    }
  }
  #pragma unroll
  for (int j=0;j<4;j++){
    int row=m0+rt*4+j;
    #pragma unroll
    for (int l=0;l<4;l++){
      int col=n0+ct*4+l;
      hst[(size_t)row*HH+col]=tanh1(acc[j][l]+bb[col]);
    }
  }
}

// Bootstrap: q0 = h0@Wq, gh0 = h0@Whh, zero nll. grid(32), block 256.
__global__ __launch_bounds__(256) void k_boot(
    const float* __restrict__ hst, const u16* __restrict__ whh,
    const u16* __restrict__ wq, float* __restrict__ ghg,
    float* __restrict__ qg, float* __restrict__ nll)
{
  __shared__ u16 hsb[16][264];
  int bx=blockIdx.x, tid=threadIdx.x;
  int wv=tid>>6, lane=tid&63, l15=lane&15, kg=(lane>>4)*8;
  int b0=bx*16;
  {
    int c=tid;
    for (int r=0;r<16;r++) hsb[r][c] = f2b(hst[(size_t)(b0+r)*HH + c]);
  }
  if (tid<16) nll[b0+tid] = 0.f;
  __syncthreads();
  int rr = (lane>>4)*4;
  for (int nt=0;nt<12;nt++){
    int n0 = wv*192 + nt*16;
    f32x4 acc = (f32x4){0.f,0.f,0.f,0.f};
    for (int ko=0;ko<256;ko+=32){
      s16x8 a = *(const s16x8*)&hsb[l15][ko+kg];
      s16x8 bf = *(const s16x8*)(whh + (size_t)(n0+l15)*HH + ko + kg);
      acc = MFMA(a, bf, acc, 0,0,0);
    }
    #pragma unroll
    for (int jr=0;jr<4;jr++)
      ghg[(size_t)(b0+rr+jr)*H3 + n0 + l15] = acc[jr];
  }
  #pragma unroll
  for (int nt=0;nt<4;nt++){
    int n0 = wv*64 + nt*16;
    f32x4 acc = (f32x4){0.f,0.f,0.f,0.f};
    for (int ko=0;ko<256;ko+=32){
      s16x8 a = *(const s16x8*)&hsb[l15][ko+kg];
      s16x8 bf = *(const s16x8*)(wq + (size_t)(n0+l15)*HH + ko + kg);
      acc = MFMA(a, bf, acc, 0,0,0);
    }
    #pragma unroll
    for (int jr=0;jr<4;jr++)
      qg[(size_t)(b0+rr+jr)*HH + n0 + l15] = acc[jr];
  }
}

// ---------------------------------------------------------------------------
// Per-step kernel. grid(512) x 512 (2 blocks/CU).
// Blocks 0..31 (L>0): load gic/pc rows (prev launch), gates->h_L, publish q_L
// (flag), then gh/pre/logits/nll off critical path. ALL blocks: attention row
// bx for step L: e/softmax, then gic_L/pc_L = a @ enc_ih / a @ enc_pc.
__global__ __launch_bounds__(512,4) void k_step(int L,
    const int* __restrict__ input,
    const float* __restrict__ tab_dec, const float* __restrict__ tab_pre,
    const float* __restrict__ bhh, const float* __restrict__ We,
    const u16* __restrict__ whh, const u16* __restrict__ wq,
    const u16* __restrict__ wph, const u16* __restrict__ wgen,
    const u16* __restrict__ pk, const u16* __restrict__ eih,
    const u16* __restrict__ epc,
    float* __restrict__ hst, u32* __restrict__ qgu, float* __restrict__ ghg,
    u16* __restrict__ gicW, const u16* __restrict__ gicR,
    u16* __restrict__ pcW, const u16* __restrict__ pcR,
    float* __restrict__ nll, u32* __restrict__ fl)
{
  __shared__ __align__(16) char smem[54400];
  // gemm views
  u16 (*gicL)[776] = (u16(*)[776])smem;                 // 24832
  u16 (*pcl)[264]  = (u16(*)[264])(smem+24832);         //  8448
  u16 (*hsb)[264]  = (u16(*)[264])(smem+33280);         //  8448
  u16 (*preb)[264] = (u16(*)[264])(smem+41728);         //  8448
  float (*lgt)[64] = (float(*)[64])(smem+50176);        //  4096
  int* stokL       = (int*)(smem+54272);                //    64
  // attn views
  float* aL  = (float*)smem;                            // 512
  int* stok  = (int*)(smem+512);                        // 512
  float* qS  = (float*)(smem+1024);                     // 1024
  float (*pG)[768] = (float(*)[768])(smem+2048);        // 24576
  float (*pP)[256] = (float(*)[256])(smem+26624);       //  8192

  int bx=blockIdx.x, tid=threadIdx.x;
  int wv=tid>>6, lane=tid&63, l15=lane&15, kg=(lane>>4)*8;

  // ======== GEMM part: blocks 0..31, step s=L-1 ========
  if (bx < 32 && L > 0){
    int s = L-1;
    int b0 = bx*16;
    int rr = (lane>>4)*4;
    float b_r, b_z, b_n;
    { int c=tid&255; b_r=bhh[c]; b_z=bhh[c+256]; b_n=bhh[c+512]; }
    for (int idx=tid; idx<1536; idx+=512){
      int r=idx/96, cc=(idx%96)*8;
      *(u32x4*)&gicL[r][cc] = *(const u32x4*)(gicR + (size_t)(b0+r)*H3 + cc);
    }
    { int r=tid>>5, cc=(tid&31)*8;
      *(u32x4*)&pcl[r][cc] = *(const u32x4*)(pcR + (size_t)(b0+r)*HH + cc); }
    if (tid<16) stokL[tid] = input[(b0+tid)*TT + s];
    __syncthreads();
    // gates -> h_L (gic from LDS — no GEMM on critical path)
    {
      int c = tid&255, rh = tid>>8;
      for (int r=rh*8; r<rh*8+8; r++){
        int bb = b0+r;
        const float* tg = tab_dec + (size_t)stokL[r]*H3;
        const float* gr = ghg + (size_t)bb*H3;
        float rg = sigm(tg[c]     + b2f(gicL[r][c])     + gr[c]     + b_r);
        float zg = sigm(tg[c+256] + b2f(gicL[r][c+256]) + gr[c+256] + b_z);
        float ng = tanh1(tg[c+512] + b2f(gicL[r][c+512]) + rg*(gr[c+512] + b_n));
        float hv = (1.f-zg)*ng + zg*hst[(size_t)bb*HH + c];
        hst[(size_t)bb*HH + c] = hv;
        hsb[r][c] = f2b(hv);
      }
    }
    __syncthreads();
    // q_L (ko-outer) -> agent stores -> flag
    {
      f32x4 accq[2];
      accq[0]=(f32x4){0.f,0.f,0.f,0.f}; accq[1]=(f32x4){0.f,0.f,0.f,0.f};
      #pragma unroll
      for (int ko=0;ko<256;ko+=32){
        s16x8 bq0 = *(const s16x8*)(wq + (size_t)(wv*32+l15)*HH + ko + kg);
        s16x8 bq1 = *(const s16x8*)(wq + (size_t)(wv*32+16+l15)*HH + ko + kg);
        s16x8 a = *(const s16x8*)&hsb[l15][ko+kg];
        accq[0] = MFMA(a,bq0,accq[0],0,0,0);
        accq[1] = MFMA(a,bq1,accq[1],0,0,0);
      }
      #pragma unroll
      for (int nt=0;nt<2;nt++)
        #pragma unroll
        for (int jr=0;jr<4;jr++)
          astore(qgu + (size_t)(b0+rr+jr)*HH + wv*32+nt*16+l15,
                 __float_as_uint(accq[nt][jr]));
    }
    __syncthreads();
    if (tid==0) astore(&fl[QF(bx)], (u32)L);
    // gh_L (N=768, ko-outer, private)
    {
      f32x4 acc6[6];
      #pragma unroll
      for (int nt=0;nt<6;nt++) acc6[nt]=(f32x4){0.f,0.f,0.f,0.f};
      #pragma unroll
      for (int ko=0;ko<256;ko+=32){
        s16x8 b6[6];
        #pragma unroll
        for (int nt=0;nt<6;nt++)
          b6[nt] = *(const s16x8*)(whh + (size_t)(wv*96+nt*16+l15)*HH + ko + kg);
        s16x8 a = *(const s16x8*)&hsb[l15][ko+kg];
        #pragma unroll
        for (int nt=0;nt<6;nt++) acc6[nt]=MFMA(a,b6[nt],acc6[nt],0,0,0);
      }
      #pragma unroll
      for (int nt=0;nt<6;nt++)
        #pragma unroll
        for (int jr=0;jr<4;jr++)
          ghg[(size_t)(b0+rr+jr)*H3 + wv*96+nt*16+l15] = acc6[nt][jr];
    }
    // pre = tab_pre + pc + h @ wph^T
    {
      f32x4 accp[2];
      accp[0]=(f32x4){0.f,0.f,0.f,0.f}; accp[1]=(f32x4){0.f,0.f,0.f,0.f};
      #pragma unroll
      for (int ko=0;ko<256;ko+=32){
        s16x8 bp0 = *(const s16x8*)(wph + (size_t)(wv*32+l15)*HH + ko + kg);
        s16x8 bp1 = *(const s16x8*)(wph + (size_t)(wv*32+16+l15)*HH + ko + kg);
        s16x8 a = *(const s16x8*)&hsb[l15][ko+kg];
        accp[0] = MFMA(a,bp0,accp[0],0,0,0);
        accp[1] = MFMA(a,bp1,accp[1],0,0,0);
      }
      #pragma unroll
      for (int nt=0;nt<2;nt++)
        #pragma unroll
        for (int jr=0;jr<4;jr++){
          int r = rr+jr, col = wv*32+nt*16+l15;
          float pv = accp[nt][jr] + b2f(pcl[r][col]) + tab_pre[(size_t)stokL[r]*HH + col];
          preb[r][col] = f2b(pv);
        }
    }
    __syncthreads();
    // logits (waves 0..3)
    if (wv<4){
      int n0 = wv*16;
      f32x4 acc = (f32x4){0.f,0.f,0.f,0.f};
      for (int ko=0;ko<256;ko+=32){
        s16x8 a = *(const s16x8*)&preb[l15][ko+kg];
        s16x8 bf = *(const s16x8*)(wgen + (size_t)(n0+l15)*HH + ko + kg);
        acc = MFMA(a,bf,acc,0,0,0);
      }
      #pragma unroll
      for (int jr=0;jr<4;jr++) lgt[rr+jr][n0+l15] = acc[jr];
    }
    __syncthreads();
    // nll
    {
      int r = wv*4 + (lane>>4);
      if (r < 16){
        float v0 = lgt[r][l15];
        float v1 = lgt[r][l15+16];
        float v2 = (l15<7)? lgt[r][l15+32] : NEGF;
        float m = fmaxf(fmaxf(v0,v1),v2);
        #pragma unroll
        for (int off=8; off; off>>=1) m = fmaxf(m, __shfl_xor(m,off));
        float pe = __expf(v0-m) + __expf(v1-m) + ((l15<7)? __expf(v2-m) : 0.f);
        #pragma unroll
        for (int off=8; off; off>>=1) pe += __shfl_xor(pe,off);
        if (l15==0){
          int ty = input[(b0+r)*TT + s+1];
          if (ty != 0) nll[b0+r] += m + __logf(pe) - lgt[r][ty];
        }
      }
    }
    __syncthreads();
  }

  // ======== Attention part: all blocks, row bx, step L ========
  if (L < TM1){
    int r2 = bx;
    int g2 = r2>>4;
    int l32 = lane&31;
    if (tid < TT) stok[tid] = input[r2*TT + tid];
    const u16* pkb = pk + (size_t)r2*TT*HH + l32*8;
    s16x8 kv[8];
    #pragma unroll
    for (int it=0; it<8; it++){
      int t = wv*16 + it*2 + (lane>>5);
      kv[it] = *(const s16x8*)(pkb + (size_t)t*HH);
    }
    float4 w0 = *(const float4*)(We + l32*8);
    float4 w1 = *(const float4*)(We + l32*8 + 4);
    __syncthreads();
    if (L > 0){
      if (tid==0){
        while (aload(&fl[QF(g2)]) < (u32)L) __builtin_amdgcn_s_sleep(1);
      }
      __syncthreads();
    }
    if (tid < 256) qS[tid] = __uint_as_float(aload(qgu + (size_t)r2*HH + tid));
    __syncthreads();
    float4 q0 = *(const float4*)&qS[l32*8];
    float4 q1 = *(const float4*)&qS[l32*8 + 4];
    #pragma unroll
    for (int it=0; it<8; it++){
      int t = wv*16 + it*2 + (lane>>5);
      s16x8 k8 = kv[it];
      float sE = tanh1(q0.x + b2f((u16)k8[0]))*w0.x
               + tanh1(q0.y + b2f((u16)k8[1]))*w0.y
               + tanh1(q0.z + b2f((u16)k8[2]))*w0.z
               + tanh1(q0.w + b2f((u16)k8[3]))*w0.w
               + tanh1(q1.x + b2f((u16)k8[4]))*w1.x
               + tanh1(q1.y + b2f((u16)k8[5]))*w1.y
               + tanh1(q1.z + b2f((u16)k8[6]))*w1.z
               + tanh1(q1.w + b2f((u16)k8[7]))*w1.w;
      #pragma unroll
      for (int off=16; off; off>>=1) sE += __shfl_xor(sE, off);
      if (l32==0) aL[t] = stok[t] ? sE : NEGF;
    }
    __syncthreads();
    if (wv==0){
      float v0 = aL[lane], v1 = aL[64+lane];
      float m = fmaxf(v0,v1);
      #pragma unroll
      for (int off=32; off; off>>=1) m = fmaxf(m, __shfl_xor(m,off));
      float p0 = __expf(v0-m), p1 = __expf(v1-m);
      float sS = p0+p1;
      #pragma unroll
      for (int off=32; off; off>>=1) sS += __shfl_xor(sS,off);
      float inv = 1.f/sS;
      aL[lane] = p0*inv; aL[64+lane] = p1*inv;
    }
    __syncthreads();
    // gic_L = a @ enc_ih row ; pc_L = a @ enc_pc row (wave: 16 t's)
    {
      float gA[8], gB[4], pA[4];
      #pragma unroll
      for (int e=0;e<8;e++) gA[e]=0.f;
      #pragma unroll
      for (int e=0;e<4;e++){ gB[e]=0.f; pA[e]=0.f; }
      const u16* ei = eih + (size_t)r2*TT*H3;
      const u16* ep = epc + (size_t)r2*TT*HH;
      int t0 = wv*16;
      for (int tt=0; tt<16; tt++){
        int t = t0+tt;
        float a = aL[t];
        u32x4 v0 = *(const u32x4*)(ei + (size_t)t*H3 + lane*8);
        u32x2 v1 = *(const u32x2*)(ei + (size_t)t*H3 + 512 + lane*4);
        u32x2 v2 = *(const u32x2*)(ep + (size_t)t*HH + lane*4);
        gA[0]+=a*bfl(v0.x); gA[1]+=a*bfh(v0.x);
        gA[2]+=a*bfl(v0.y); gA[3]+=a*bfh(v0.y);
        gA[4]+=a*bfl(v0.z); gA[5]+=a*bfh(v0.z);
        gA[6]+=a*bfl(v0.w); gA[7]+=a*bfh(v0.w);
        gB[0]+=a*bfl(v1.x); gB[1]+=a*bfh(v1.x);
        gB[2]+=a*bfl(v1.y); gB[3]+=a*bfh(v1.y);
        pA[0]+=a*bfl(v2.x); pA[1]+=a*bfh(v2.x);
        pA[2]+=a*bfl(v2.y); pA[3]+=a*bfh(v2.y);
      }
      #pragma unroll
      for (int e=0;e<8;e++) pG[wv][lane*8+e] = gA[e];
      #pragma unroll
      for (int e=0;e<4;e++) pG[wv][512+lane*4+e] = gB[e];
      #pragma unroll
      for (int e=0;e<4;e++) pP[wv][lane*4+e] = pA[e];
    }
    __syncthreads();
    {
      float sG = 0.f;
      #pragma unroll
      for (int w=0;w<8;w++) sG += pG[w][tid];
      gicW[(size_t)r2*H3 + tid] = f2b(sG);
      if (tid < 256){
        float sH = 0.f;
        #pragma unroll
        for (int w=0;w<8;w++) sH += pG[w][512+tid];
        gicW[(size_t)r2*H3 + 512 + tid] = f2b(sH);
      } else {
        int d = tid-256;
        float sP = 0.f;
        #pragma unroll
        for (int w=0;w<8;w++) sP += pP[w][d];
        pcW[(size_t)r2*HH + d] = f2b(sP);
      }
    }
  }
}

__global__ __launch_bounds__(256) void k_loss(const float* __restrict__ nll,
                                              float* __restrict__ out)
{
  __shared__ float sm[256];
  int tid=threadIdx.x;
  float s = nll[tid] + nll[tid+256];
  sm[tid]=s; __syncthreads();
  for (int off=128; off; off>>=1){
    if (tid<off) sm[tid]+=sm[tid+off];
    __syncthreads();
  }
  if (tid==0) out[0]=sm[0];
}

extern "C" void kernel_launch(void* const* d_in, const int* in_sizes, int n_in,
                              void* d_out, int out_size, void* d_ws, size_t ws_size,
                              hipStream_t stream)
{
  const int*   input    = (const int*)  d_in[0];
  const float* src_emb  = (const float*)d_in[1];
  const float* trg_emb  = (const float*)d_in[2];
  const float* eWih_f   = (const float*)d_in[3];
  const float* eWhh_f   = (const float*)d_in[4];
  const float* ebih_f   = (const float*)d_in[5];
  const float* ebhh_f   = (const float*)d_in[6];
  const float* eWih_b   = (const float*)d_in[7];
  const float* eWhh_b   = (const float*)d_in[8];
  const float* ebih_b   = (const float*)d_in[9];
  const float* ebhh_b   = (const float*)d_in[10];
  const float* bridge_W = (const float*)d_in[11];
  const float* bridge_b = (const float*)d_in[12];
  const float* attn_Wk  = (const float*)d_in[13];
  const float* attn_Wq  = (const float*)d_in[14];
  const float* attn_We  = (const float*)d_in[15];
  const float* dec_Wih  = (const float*)d_in[16];
  const float* dec_Whh  = (const float*)d_in[17];
  const float* dec_bih  = (const float*)d_in[18];
  const float* dec_bhh  = (const float*)d_in[19];
  const float* pre_W    = (const float*)d_in[20];
  const float* gen_W    = (const float*)d_in[21];

  float* F = (float*)d_ws;
  size_t o=0;
  u32* fl         = (u32*)(F+o); o+=2048;
  float* tab_gi_f = F+o; o+=(size_t)VV*H3;
  float* tab_gi_b = F+o; o+=(size_t)VV*H3;
  float* tab_dec  = F+o; o+=(size_t)VV*H3;
  float* tab_pre  = F+o; o+=(size_t)VV*HH;
  float* h_f      = F+o; o+=(size_t)BB*HH;
  float* h_b      = F+o; o+=(size_t)BB*HH;
  float* hst      = F+o; o+=(size_t)BB*HH;
  float* qg       = F+o; o+=(size_t)BB*HH;
  float* ghg      = F+o; o+=(size_t)BB*H3;
  float* nll      = F+o; o+=(size_t)BB;
  u16* U = (u16*)(F+o);
  size_t uo=0;
  u16* enc_out = U+uo; uo+=(size_t)BB*TT*H2;
  u16* pk      = U+uo; uo+=(size_t)BB*TT*HH;
  u16* eih     = U+uo; uo+=(size_t)BB*TT*H3;
  u16* epc     = U+uo; uo+=(size_t)BB*TT*HH;
  u16* gic0    = U+uo; uo+=(size_t)BB*H3;
  u16* gic1    = U+uo; uo+=(size_t)BB*H3;
  u16* pc0     = U+uo; uo+=(size_t)BB*HH;
  u16* pc1     = U+uo; uo+=(size_t)BB*HH;
  u16* wb_ehh_f= U+uo; uo+=(size_t)H3*HH;
  u16* wb_ehh_b= U+uo; uo+=(size_t)H3*HH;
  u16* wb_dhh  = U+uo; uo+=(size_t)H3*HH;
  u16* wb_dih  = U+uo; uo+=(size_t)H3*H2;
  u16* wb_wk   = U+uo; uo+=(size_t)HH*H2;
  u16* wb_wq   = U+uo; uo+=(size_t)HH*HH;
  u16* wb_ph   = U+uo; uo+=(size_t)HH*HH;
  u16* wb_pc   = U+uo; uo+=(size_t)HH*H2;
  u16* wb_gen  = U+uo; uo+=(size_t)64*HH;

  dim3 blk(256,1,1);
  k_tables<<<dim3(VV,10),blk,0,stream>>>(src_emb,trg_emb,eWih_f,ebih_f,eWih_b,ebih_b,
                                         dec_Wih,dec_bih,pre_W,
                                         tab_gi_f,tab_gi_b,tab_dec,tab_pre);
  k_cvt_all<<<dim3(5440),blk,0,stream>>>(eWhh_f,eWhh_b,dec_Whh,dec_Wih,attn_Wk,attn_Wq,pre_W,gen_W,
                                         wb_ehh_f,wb_ehh_b,wb_dhh,wb_dih,wb_wk,wb_wq,
                                         wb_ph,wb_pc,wb_gen);
  k_enc_all<<<dim3(32),dim3(512),0,stream>>>(input,wb_ehh_f,wb_ehh_b,ebhh_f,ebhh_b,
                                             tab_gi_f,tab_gi_b,h_f,h_b,enc_out);
  k_proj<<<dim3(1024,1),blk,0,stream>>>(enc_out,wb_wk,pk,HH);
  k_proj<<<dim3(1024,3),blk,0,stream>>>(enc_out,wb_dih,eih,H3);
  k_proj<<<dim3(1024,1),blk,0,stream>>>(enc_out,wb_pc,epc,HH);
  k_bridge<<<dim3(4,8),blk,0,stream>>>(h_f,h_b,bridge_W,bridge_b,hst);
  k_boot<<<dim3(32),blk,0,stream>>>(hst,wb_dhh,wb_wq,ghg,qg,nll);
  hipMemsetAsync(fl, 0, 8192, stream);

  for (int L=0; L<=TM1; L++){
    u16* gw = (L&1)? gic1 : gic0;
    u16* gr = (L&1)? gic0 : gic1;
    u16* pw = (L&1)? pc1 : pc0;
    u16* pr = (L&1)? pc0 : pc1;
    k_step<<<dim3(512),dim3(512),0,stream>>>(L,input,tab_dec,tab_pre,dec_bhh,attn_We,
                                             wb_dhh,wb_wq,wb_ph,wb_gen,
                                             pk,eih,epc,hst,(u32*)qg,ghg,
                                             gw,gr,pw,pr,nll,fl);
  }
  k_loss<<<dim3(1),blk,0,stream>>>(nll,(float*)d_out);
}

// Round 14
// 8778.210 us; speedup vs baseline: 4.5265x; 1.0521x over previous
//
#include <hip/hip_runtime.h>

#define BB 512
#define TT 128
#define EE 512
#define HH 256
#define VV 39
#define H3 768
#define H2 512
#define TM1 127
#define NEGF (-3.402823466e38f)

typedef unsigned short u16;
typedef unsigned int u32;
typedef __attribute__((ext_vector_type(8))) short s16x8;
typedef __attribute__((ext_vector_type(4))) float f32x4;
typedef __attribute__((ext_vector_type(2))) unsigned int u32x2;
typedef __attribute__((ext_vector_type(4))) unsigned int u32x4;

__device__ __forceinline__ float b2f(u16 u){ u32 x=((u32)u)<<16; return __uint_as_float(x); }
__device__ __forceinline__ u16 f2b(float f){ u32 x=__float_as_uint(f); u32 r=(x+0x7fffu+((x>>16)&1u))>>16; return (u16)r; }
__device__ __forceinline__ float sigm(float x){ return 1.f/(1.f+__expf(-x)); }
__device__ __forceinline__ float tanh1(float x){ float t=__expf(2.f*x); return 1.f-2.f/(t+1.f); }
__device__ __forceinline__ float bfl(u32 u){ return __uint_as_float(u<<16); }
__device__ __forceinline__ float bfh(u32 u){ return __uint_as_float(u & 0xffff0000u); }

#define MFMA __builtin_amdgcn_mfma_f32_16x16x32_bf16

__device__ __forceinline__ u32 aload(const u32* p){
  return __hip_atomic_load(p, __ATOMIC_RELAXED, __HIP_MEMORY_SCOPE_AGENT);
}
__device__ __forceinline__ void astore(u32* p, u32 v){
  __hip_atomic_store(p, v, __ATOMIC_RELAXED, __HIP_MEMORY_SCOPE_AGENT);
}
#define QF(g) ((g)*16)

// ---------------------------------------------------------------------------
__global__ __launch_bounds__(256) void k_tables(
    const float* __restrict__ src_emb, const float* __restrict__ trg_emb,
    const float* __restrict__ Wih_f, const float* __restrict__ bih_f,
    const float* __restrict__ Wih_b, const float* __restrict__ bih_b,
    const float* __restrict__ dec_Wih, const float* __restrict__ dec_bih,
    const float* __restrict__ pre_W,
    float* __restrict__ tab_gi_f, float* __restrict__ tab_gi_b,
    float* __restrict__ tab_dec, float* __restrict__ tab_pre)
{
  int v = blockIdx.x;
  int y = blockIdx.y;
  int tid = threadIdx.x;
  if (y < 9){
    int seg = y/3, part = y%3;
    int n = part*256 + tid;
    const float* emb; const float* W; const float* bias; float* out; int ldw;
    if (seg==0){ emb=src_emb; W=Wih_f; bias=bih_f; out=tab_gi_f; ldw=EE; }
    else if (seg==1){ emb=src_emb; W=Wih_b; bias=bih_b; out=tab_gi_b; ldw=EE; }
    else { emb=trg_emb; W=dec_Wih; bias=dec_bih; out=tab_dec; ldw=EE+H2; }
    float acc = bias[n];
    const float* er = emb + (size_t)v*EE;
    const float* wr = W + (size_t)n*ldw;
    for (int k=0;k<EE;k++) acc += er[k]*wr[k];
    out[(size_t)v*H3 + n] = acc;
  } else {
    int n = tid;
    float acc = 0.f;
    const float* er = trg_emb + (size_t)v*EE;
    const float* wr = pre_W + (size_t)n*1280;
    for (int k=0;k<EE;k++) acc += er[k]*wr[k];
    tab_pre[(size_t)v*HH + n] = acc;
  }
}

// All fp32->bf16 weight conversions. grid(5440).
__global__ __launch_bounds__(256) void k_cvt_all(
    const float* __restrict__ eWhh_f, const float* __restrict__ eWhh_b,
    const float* __restrict__ dWhh, const float* __restrict__ dWih,
    const float* __restrict__ Wk, const float* __restrict__ Wq,
    const float* __restrict__ preW, const float* __restrict__ genW,
    u16* __restrict__ o1, u16* __restrict__ o2, u16* __restrict__ o3,
    u16* __restrict__ o4, u16* __restrict__ o5, u16* __restrict__ o6,
    u16* __restrict__ o7, u16* __restrict__ o8, u16* __restrict__ o9)
{
  int idx = blockIdx.x*256 + threadIdx.x;
  const float* src; u16* dst; int cols, ld, off, rel;
  if      (idx <  196608){ rel=idx;          src=eWhh_f; dst=o1; cols=256; ld=256;  off=0;   }
  else if (idx <  393216){ rel=idx-196608;   src=eWhh_b; dst=o2; cols=256; ld=256;  off=0;   }
  else if (idx <  589824){ rel=idx-393216;   src=dWhh;   dst=o3; cols=256; ld=256;  off=0;   }
  else if (idx <  983040){ rel=idx-589824;   src=dWih;   dst=o4; cols=512; ld=1024; off=512; }
  else if (idx < 1114112){ rel=idx-983040;   src=Wk;     dst=o5; cols=512; ld=512;  off=0;   }
  else if (idx < 1179648){ rel=idx-1114112;  src=Wq;     dst=o6; cols=256; ld=256;  off=0;   }
  else if (idx < 1245184){ rel=idx-1179648;  src=preW;   dst=o7; cols=256; ld=1280; off=512; }
  else if (idx < 1376256){ rel=idx-1245184;  src=preW;   dst=o8; cols=512; ld=1280; off=768; }
  else if (idx < 1392640){
    rel=idx-1376256; int r=rel>>8, c2=rel&255;
    o9[rel] = (r<VV)? f2b(genW[(size_t)r*HH + c2]) : (u16)0;
    return;
  }
  else return;
  int r = rel/cols, c2 = rel - r*cols;
  dst[rel] = f2b(src[(size_t)r*ld + off + c2]);
}

// ---------------------------------------------------------------------------
// WHOLE encoder. grid(128): bx = dir*64 + mt (8-row tile). block 512.
__global__ __launch_bounds__(512) void k_enc_all(const int* __restrict__ input,
    const u16* __restrict__ wb_f, const u16* __restrict__ wb_b,
    const float* __restrict__ bhh_f, const float* __restrict__ bhh_b,
    const float* __restrict__ tab_f, const float* __restrict__ tab_b,
    float* __restrict__ h_f, float* __restrict__ h_b, u16* __restrict__ enc_out)
{
  __shared__ float gh[8][772];
  __shared__ u16 hs[16][264];    // rows 8..15 stay zero (MFMA M-pad)
  int bx = blockIdx.x;
  int dirb = bx>>6, mt = bx&63;
  int m0 = mt*8;
  int tid = threadIdx.x;
  const float* tab = dirb? tab_b : tab_f;
  const float* bhh = dirb? bhh_b : bhh_f;
  const u16* Wb = dirb? wb_b : wb_f;
  int c = tid & 255, rh = tid>>8;
  float b_r=bhh[c], b_z=bhh[c+256], b_n=bhh[c+512];
  float hreg[4];
  #pragma unroll
  for (int r=0;r<4;r++) hreg[r]=0.f;
  int wv = tid>>6, lane = tid&63, l15 = lane&15, kg=(lane>>4)*8;
  int n0w = wv*96;
  float* hOut = dirb? h_b : h_f;
  { u16* z = &hs[0][0]; for (int e=tid; e<16*264; e+=512) z[e]=0; }
  __syncthreads();

  for (int s=1; s<=TT; s++){
    int tcol = dirb? (TT-s) : (s-1);
    #pragma unroll
    for (int r=0;r<4;r++){
      int row = rh*4 + r;
      int b = m0 + row;
      int tok = input[b*TT + tcol];
      const float* tg = tab + (size_t)tok*H3;
      float g0=0.f, g1=0.f, g2=0.f;
      if (s>1){ g0=gh[row][c]; g1=gh[row][c+256]; g2=gh[row][c+512]; }
      float rg = sigm(tg[c]     + g0 + b_r);
      float zg = sigm(tg[c+256] + g1 + b_z);
      float ng = tanh1(tg[c+512] + rg*(g2 + b_n));
      float hv = (1.f-zg)*ng + zg*hreg[r];
      hreg[r] = hv;
      u16 hb = f2b(hv);
      hs[row][c] = hb;
      enc_out[((size_t)b*TT + tcol)*H2 + (size_t)dirb*HH + c] = hb;
    }
    if (s==TT){
      #pragma unroll
      for (int r=0;r<4;r++)
        hOut[(size_t)(m0+rh*4+r)*HH + c] = hreg[r];
      break;
    }
    __syncthreads();
    f32x4 acc[6];
    #pragma unroll
    for (int nt=0;nt<6;nt++) acc[nt]=(f32x4){0.f,0.f,0.f,0.f};
    const u16* ar0 = &hs[l15][0];
    s16x8 bcur[6], bnext[6];
    #pragma unroll
    for (int nt=0;nt<6;nt++)
      bcur[nt] = *(const s16x8*)(Wb + (size_t)(n0w+nt*16+l15)*HH + kg);
    #pragma unroll
    for (int ko=0;ko<256;ko+=32){
      if (ko<224){
        #pragma unroll
        for (int nt=0;nt<6;nt++)
          bnext[nt] = *(const s16x8*)(Wb + (size_t)(n0w+nt*16+l15)*HH + ko+32 + kg);
      }
      s16x8 a0 = *(const s16x8*)(ar0 + ko + kg);
      #pragma unroll
      for (int nt=0;nt<6;nt++)
        acc[nt] = MFMA(a0, bcur[nt], acc[nt], 0,0,0);
      #pragma unroll
      for (int nt=0;nt<6;nt++) bcur[nt]=bnext[nt];
    }
    int q4 = (lane>>4)*4;
    if (q4 < 8){
      #pragma unroll
      for (int nt=0;nt<6;nt++){
        int col = n0w + nt*16 + l15;
        #pragma unroll
        for (int j=0;j<4;j++)
          gh[q4 + j][col] = acc[nt][j];
      }
    }
    __syncthreads();
  }
}

// out[m][n] = enc[m] . W[n]  (K=512). W row-major [nTot][512].
__global__ __launch_bounds__(256) void k_proj(const u16* __restrict__ enc,
    const u16* __restrict__ W, u16* __restrict__ out, int nTot)
{
  int m0 = blockIdx.x*64;
  int tid = threadIdx.x, wv = tid>>6, lane = tid&63;
  int l15 = lane&15, kg = (lane>>4)*8;
  int n0 = blockIdx.y*256 + wv*64;
  f32x4 acc[4][4];
  #pragma unroll
  for (int rt=0;rt<4;rt++)
    #pragma unroll
    for (int nt=0;nt<4;nt++) acc[rt][nt] = (f32x4){0.f,0.f,0.f,0.f};
  for (int ko=0; ko<512; ko+=32){
    s16x8 a[4], b[4];
    #pragma unroll
    for (int rt=0;rt<4;rt++) a[rt] = *(const s16x8*)(enc + (size_t)(m0+rt*16+l15)*H2 + ko + kg);
    #pragma unroll
    for (int nt=0;nt<4;nt++) b[nt] = *(const s16x8*)(W + (size_t)(n0+nt*16+l15)*H2 + ko + kg);
    #pragma unroll
    for (int rt=0;rt<4;rt++)
      #pragma unroll
      for (int nt=0;nt<4;nt++)
        acc[rt][nt] = MFMA(a[rt], b[nt], acc[rt][nt], 0,0,0);
  }
  #pragma unroll
  for (int rt=0;rt<4;rt++){
    int rbase = m0 + rt*16 + (lane>>4)*4;
    #pragma unroll
    for (int nt=0;nt<4;nt++){
      int col = n0 + nt*16 + l15;
      #pragma unroll
      for (int j=0;j<4;j++)
        out[(size_t)(rbase+j)*nTot + col] = f2b(acc[rt][nt][j]);
    }
  }
}

// hidden = tanh([h_f|h_b] @ bridge_W^T + b) -> hst. grid (4,8).
__global__ __launch_bounds__(256) void k_bridge(const float* __restrict__ h_f,
    const float* __restrict__ h_b, const float* __restrict__ bw,
    const float* __restrict__ bb, float* __restrict__ hst)
{
  __shared__ float As[32][68];
  __shared__ float Ws[32][68];
  int n0=blockIdx.x*64, m0=blockIdx.y*64, tid=threadIdx.x;
  int ar=tid>>2, ak=(tid&3)*8;
  int rt=tid>>4, ct=tid&15;
  float acc[4][4];
  #pragma unroll
  for (int j=0;j<4;j++){
    #pragma unroll
    for (int l=0;l<4;l++) acc[j][l]=0.f;
  }
  for (int ko=0;ko<512;ko+=32){
    int k0=ko+ak;
    const float* asrc = (k0<256)? (h_f + (size_t)(m0+ar)*HH + k0)
                                : (h_b + (size_t)(m0+ar)*HH + (k0-256));
    float4 a0=*(const float4*)asrc, a1=*(const float4*)(asrc+4);
    const float* wsrc = bw + (size_t)(n0+ar)*H2 + k0;
    float4 w0=*(const float4*)wsrc, w1=*(const float4*)(wsrc+4);
    __syncthreads();
    As[ak+0][ar]=a0.x; As[ak+1][ar]=a0.y; As[ak+2][ar]=a0.z; As[ak+3][ar]=a0.w;
    As[ak+4][ar]=a1.x; As[ak+5][ar]=a1.y; As[ak+6][ar]=a1.z; As[ak+7][ar]=a1.w;
    Ws[ak+0][ar]=w0.x; Ws[ak+1][ar]=w0.y; Ws[ak+2][ar]=w0.z; Ws[ak+3][ar]=w0.w;
    Ws[ak+4][ar]=w1.x; Ws[ak+5][ar]=w1.y; Ws[ak+6][ar]=w1.z; Ws[ak+7][ar]=w1.w;
    __syncthreads();
    #pragma unroll
    for (int kk=0;kk<32;kk++){
      float4 a=*(const float4*)&As[kk][rt*4];
      float4 w=*(const float4*)&Ws[kk][ct*4];
      float a4[4]={a.x,a.y,a.z,a.w};
      float w4[4]={w.x,w.y,w.z,w.w};
      #pragma unroll
      for (int j=0;j<4;j++){
        #pragma unroll
        for (int l=0;l<4;l++) acc[j][l]+=a4[j]*w4[l];
      }
    }
  }
  #pragma unroll
  for (int j=0;j<4;j++){
    int row=m0+rt*4+j;
    #pragma unroll
    for (int l=0;l<4;l++){
      int col=n0+ct*4+l;
      hst[(size_t)row*HH+col]=tanh1(acc[j][l]+bb[col]);
    }
  }
}

// Bootstrap: q0 = h0@Wq, gh0 = h0@Whh, zero nll. grid(32), block 256.
__global__ __launch_bounds__(256) void k_boot(
    const float* __restrict__ hst, const u16* __restrict__ whh,
    const u16* __restrict__ wq, float* __restrict__ ghg,
    float* __restrict__ qg, float* __restrict__ nll)
{
  __shared__ u16 hsb[16][264];
  int bx=blockIdx.x, tid=threadIdx.x;
  int wv=tid>>6, lane=tid&63, l15=lane&15, kg=(lane>>4)*8;
  int b0=bx*16;
  {
    int c=tid;
    for (int r=0;r<16;r++) hsb[r][c] = f2b(hst[(size_t)(b0+r)*HH + c]);
  }
  if (tid<16) nll[b0+tid] = 0.f;
  __syncthreads();
  int rr = (lane>>4)*4;
  for (int nt=0;nt<12;nt++){
    int n0 = wv*192 + nt*16;
    f32x4 acc = (f32x4){0.f,0.f,0.f,0.f};
    for (int ko=0;ko<256;ko+=32){
      s16x8 a = *(const s16x8*)&hsb[l15][ko+kg];
      s16x8 bf = *(const s16x8*)(whh + (size_t)(n0+l15)*HH + ko + kg);
      acc = MFMA(a, bf, acc, 0,0,0);
    }
    #pragma unroll
    for (int jr=0;jr<4;jr++)
      ghg[(size_t)(b0+rr+jr)*H3 + n0 + l15] = acc[jr];
  }
  #pragma unroll
  for (int nt=0;nt<4;nt++){
    int n0 = wv*64 + nt*16;
    f32x4 acc = (f32x4){0.f,0.f,0.f,0.f};
    for (int ko=0;ko<256;ko+=32){
      s16x8 a = *(const s16x8*)&hsb[l15][ko+kg];
      s16x8 bf = *(const s16x8*)(wq + (size_t)(n0+l15)*HH + ko + kg);
      acc = MFMA(a, bf, acc, 0,0,0);
    }
    #pragma unroll
    for (int jr=0;jr<4;jr++)
      qg[(size_t)(b0+rr+jr)*HH + n0 + l15] = acc[jr];
  }
}

// ---------------------------------------------------------------------------
// Per-step kernel. grid(512) x 512 (2 blocks/CU).
__global__ __launch_bounds__(512,4) void k_step(int L,
    const int* __restrict__ input,
    const float* __restrict__ tab_dec, const float* __restrict__ tab_pre,
    const float* __restrict__ bhh, const float* __restrict__ We,
    const u16* __restrict__ whh, const u16* __restrict__ wq,
    const u16* __restrict__ wph, const u16* __restrict__ wgen,
    const u16* __restrict__ pk, const u16* __restrict__ eih,
    const u16* __restrict__ epc,
    float* __restrict__ hst, u32* __restrict__ qgu, float* __restrict__ ghg,
    u16* __restrict__ gicW, const u16* __restrict__ gicR,
    u16* __restrict__ pcW, const u16* __restrict__ pcR,
    float* __restrict__ nll, u32* __restrict__ fl)
{
  __shared__ __align__(16) char smem[54400];
  // gemm views
  u16 (*gicL)[776] = (u16(*)[776])smem;                 // 24832
  u16 (*pcl)[264]  = (u16(*)[264])(smem+24832);         //  8448
  u16 (*hsb)[264]  = (u16(*)[264])(smem+33280);         //  8448
  u16 (*preb)[264] = (u16(*)[264])(smem+41728);         //  8448
  float (*lgt)[64] = (float(*)[64])(smem+50176);        //  4096
  int* stokL       = (int*)(smem+54272);                //    64
  // attn views
  float* aL  = (float*)smem;                            // 512
  int* stok  = (int*)(smem+512);                        // 512
  float* qS  = (float*)(smem+1024);                     // 1024
  float (*pG)[768] = (float(*)[768])(smem+2048);        // 24576
  float (*pP)[256] = (float(*)[256])(smem+26624);       //  8192

  int bx=blockIdx.x, tid=threadIdx.x;
  int wv=tid>>6, lane=tid&63, l15=lane&15, kg=(lane>>4)*8;

  // ======== GEMM part: blocks 0..31, step s=L-1 ========
  if (bx < 32 && L > 0){
    int s = L-1;
    int b0 = bx*16;
    int rr = (lane>>4)*4;
    float b_r, b_z, b_n;
    { int c=tid&255; b_r=bhh[c]; b_z=bhh[c+256]; b_n=bhh[c+512]; }
    for (int idx=tid; idx<1536; idx+=512){
      int r=idx/96, cc=(idx%96)*8;
      *(u32x4*)&gicL[r][cc] = *(const u32x4*)(gicR + (size_t)(b0+r)*H3 + cc);
    }
    { int r=tid>>5, cc=(tid&31)*8;
      *(u32x4*)&pcl[r][cc] = *(const u32x4*)(pcR + (size_t)(b0+r)*HH + cc); }
    if (tid<16) stokL[tid] = input[(b0+tid)*TT + s];
    __syncthreads();
    // gates -> h_L
    {
      int c = tid&255, rh = tid>>8;
      for (int r=rh*8; r<rh*8+8; r++){
        int bb = b0+r;
        const float* tg = tab_dec + (size_t)stokL[r]*H3;
        const float* gr = ghg + (size_t)bb*H3;
        float rg = sigm(tg[c]     + b2f(gicL[r][c])     + gr[c]     + b_r);
        float zg = sigm(tg[c+256] + b2f(gicL[r][c+256]) + gr[c+256] + b_z);
        float ng = tanh1(tg[c+512] + b2f(gicL[r][c+512]) + rg*(gr[c+512] + b_n));
        float hv = (1.f-zg)*ng + zg*hst[(size_t)bb*HH + c];
        hst[(size_t)bb*HH + c] = hv;
        hsb[r][c] = f2b(hv);
      }
    }
    __syncthreads();
    // q_L -> agent stores -> flag
    {
      f32x4 accq[2];
      accq[0]=(f32x4){0.f,0.f,0.f,0.f}; accq[1]=(f32x4){0.f,0.f,0.f,0.f};
      #pragma unroll
      for (int ko=0;ko<256;ko+=32){
        s16x8 bq0 = *(const s16x8*)(wq + (size_t)(wv*32+l15)*HH + ko + kg);
        s16x8 bq1 = *(const s16x8*)(wq + (size_t)(wv*32+16+l15)*HH + ko + kg);
        s16x8 a = *(const s16x8*)&hsb[l15][ko+kg];
        accq[0] = MFMA(a,bq0,accq[0],0,0,0);
        accq[1] = MFMA(a,bq1,accq[1],0,0,0);
      }
      #pragma unroll
      for (int nt=0;nt<2;nt++)
        #pragma unroll
        for (int jr=0;jr<4;jr++)
          astore(qgu + (size_t)(b0+rr+jr)*HH + wv*32+nt*16+l15,
                 __float_as_uint(accq[nt][jr]));
    }
    __syncthreads();
    if (tid==0) astore(&fl[QF(bx)], (u32)L);
    // gh_L
    {
      f32x4 acc6[6];
      #pragma unroll
      for (int nt=0;nt<6;nt++) acc6[nt]=(f32x4){0.f,0.f,0.f,0.f};
      #pragma unroll
      for (int ko=0;ko<256;ko+=32){
        s16x8 b6[6];
        #pragma unroll
        for (int nt=0;nt<6;nt++)
          b6[nt] = *(const s16x8*)(whh + (size_t)(wv*96+nt*16+l15)*HH + ko + kg);
        s16x8 a = *(const s16x8*)&hsb[l15][ko+kg];
        #pragma unroll
        for (int nt=0;nt<6;nt++) acc6[nt]=MFMA(a,b6[nt],acc6[nt],0,0,0);
      }
      #pragma unroll
      for (int nt=0;nt<6;nt++)
        #pragma unroll
        for (int jr=0;jr<4;jr++)
          ghg[(size_t)(b0+rr+jr)*H3 + wv*96+nt*16+l15] = acc6[nt][jr];
    }
    // pre = tab_pre + pc + h @ wph^T
    {
      f32x4 accp[2];
      accp[0]=(f32x4){0.f,0.f,0.f,0.f}; accp[1]=(f32x4){0.f,0.f,0.f,0.f};
      #pragma unroll
      for (int ko=0;ko<256;ko+=32){
        s16x8 bp0 = *(const s16x8*)(wph + (size_t)(wv*32+l15)*HH + ko + kg);
        s16x8 bp1 = *(const s16x8*)(wph + (size_t)(wv*32+16+l15)*HH + ko + kg);
        s16x8 a = *(const s16x8*)&hsb[l15][ko+kg];
        accp[0] = MFMA(a,bp0,accp[0],0,0,0);
        accp[1] = MFMA(a,bp1,accp[1],0,0,0);
      }
      #pragma unroll
      for (int nt=0;nt<2;nt++)
        #pragma unroll
        for (int jr=0;jr<4;jr++){
          int r = rr+jr, col = wv*32+nt*16+l15;
          float pv = accp[nt][jr] + b2f(pcl[r][col]) + tab_pre[(size_t)stokL[r]*HH + col];
          preb[r][col] = f2b(pv);
        }
    }
    __syncthreads();
    // logits (waves 0..3)
    if (wv<4){
      int n0 = wv*16;
      f32x4 acc = (f32x4){0.f,0.f,0.f,0.f};
      for (int ko=0;ko<256;ko+=32){
        s16x8 a = *(const s16x8*)&preb[l15][ko+kg];
        s16x8 bf = *(const s16x8*)(wgen + (size_t)(n0+l15)*HH + ko + kg);
        acc = MFMA(a,bf,acc,0,0,0);
      }
      #pragma unroll
      for (int jr=0;jr<4;jr++) lgt[rr+jr][n0+l15] = acc[jr];
    }
    __syncthreads();
    // nll
    {
      int r = wv*4 + (lane>>4);
      if (r < 16){
        float v0 = lgt[r][l15];
        float v1 = lgt[r][l15+16];
        float v2 = (l15<7)? lgt[r][l15+32] : NEGF;
        float m = fmaxf(fmaxf(v0,v1),v2);
        #pragma unroll
        for (int off=8; off; off>>=1) m = fmaxf(m, __shfl_xor(m,off));
        float pe = __expf(v0-m) + __expf(v1-m) + ((l15<7)? __expf(v2-m) : 0.f);
        #pragma unroll
        for (int off=8; off; off>>=1) pe += __shfl_xor(pe,off);
        if (l15==0){
          int ty = input[(b0+r)*TT + s+1];
          if (ty != 0) nll[b0+r] += m + __logf(pe) - lgt[r][ty];
        }
      }
    }
    __syncthreads();
  }

  // ======== Attention part: all blocks, row bx, step L ========
  if (L < TM1){
    int r2 = bx;
    int g2 = r2>>4;
    int l32 = lane&31;
    if (tid < TT) stok[tid] = input[r2*TT + tid];
    const u16* pkb = pk + (size_t)r2*TT*HH + l32*8;
    s16x8 kv[8];
    #pragma unroll
    for (int it=0; it<8; it++){
      int t = wv*16 + it*2 + (lane>>5);
      kv[it] = *(const s16x8*)(pkb + (size_t)t*HH);
    }
    float4 w0 = *(const float4*)(We + l32*8);
    float4 w1 = *(const float4*)(We + l32*8 + 4);
    __syncthreads();
    if (L > 0){
      if (tid==0){
        while (aload(&fl[QF(g2)]) < (u32)L) __builtin_amdgcn_s_sleep(1);
      }
      __syncthreads();
    }
    if (tid < 256) qS[tid] = __uint_as_float(aload(qgu + (size_t)r2*HH + tid));
    __syncthreads();
    float4 q0 = *(const float4*)&qS[l32*8];
    float4 q1 = *(const float4*)&qS[l32*8 + 4];
    #pragma unroll
    for (int it=0; it<8; it++){
      int t = wv*16 + it*2 + (lane>>5);
      s16x8 k8 = kv[it];
      float sE = tanh1(q0.x + b2f((u16)k8[0]))*w0.x
               + tanh1(q0.y + b2f((u16)k8[1]))*w0.y
               + tanh1(q0.z + b2f((u16)k8[2]))*w0.z
               + tanh1(q0.w + b2f((u16)k8[3]))*w0.w
               + tanh1(q1.x + b2f((u16)k8[4]))*w1.x
               + tanh1(q1.y + b2f((u16)k8[5]))*w1.y
               + tanh1(q1.z + b2f((u16)k8[6]))*w1.z
               + tanh1(q1.w + b2f((u16)k8[7]))*w1.w;
      #pragma unroll
      for (int off=16; off; off>>=1) sE += __shfl_xor(sE, off);
      if (l32==0) aL[t] = stok[t] ? sE : NEGF;
    }
    __syncthreads();
    if (wv==0){
      float v0 = aL[lane], v1 = aL[64+lane];
      float m = fmaxf(v0,v1);
      #pragma unroll
      for (int off=32; off; off>>=1) m = fmaxf(m, __shfl_xor(m,off));
      float p0 = __expf(v0-m), p1 = __expf(v1-m);
      float sS = p0+p1;
      #pragma unroll
      for (int off=32; off; off>>=1) sS += __shfl_xor(sS,off);
      float inv = 1.f/sS;
      aL[lane] = p0*inv; aL[64+lane] = p1*inv;
    }
    __syncthreads();
    // gic_L = a @ eih row ; pc_L = a @ epc row (wave: 16 t's, unrolled x4)
    {
      float gA[8], gB[4], pA[4];
      #pragma unroll
      for (int e=0;e<8;e++) gA[e]=0.f;
      #pragma unroll
      for (int e=0;e<4;e++){ gB[e]=0.f; pA[e]=0.f; }
      const u16* ei = eih + (size_t)r2*TT*H3;
      const u16* ep = epc + (size_t)r2*TT*HH;
      int t0 = wv*16;
      #pragma unroll 4
      for (int tt=0; tt<16; tt++){
        int t = t0+tt;
        float a = aL[t];
        u32x4 v0 = *(const u32x4*)(ei + (size_t)t*H3 + lane*8);
        u32x2 v1 = *(const u32x2*)(ei + (size_t)t*H3 + 512 + lane*4);
        u32x2 v2 = *(const u32x2*)(ep + (size_t)t*HH + lane*4);
        gA[0]+=a*bfl(v0.x); gA[1]+=a*bfh(v0.x);
        gA[2]+=a*bfl(v0.y); gA[3]+=a*bfh(v0.y);
        gA[4]+=a*bfl(v0.z); gA[5]+=a*bfh(v0.z);
        gA[6]+=a*bfl(v0.w); gA[7]+=a*bfh(v0.w);
        gB[0]+=a*bfl(v1.x); gB[1]+=a*bfh(v1.x);
        gB[2]+=a*bfl(v1.y); gB[3]+=a*bfh(v1.y);
        pA[0]+=a*bfl(v2.x); pA[1]+=a*bfh(v2.x);
        pA[2]+=a*bfl(v2.y); pA[3]+=a*bfh(v2.y);
      }
      #pragma unroll
      for (int e=0;e<8;e++) pG[wv][lane*8+e] = gA[e];
      #pragma unroll
      for (int e=0;e<4;e++) pG[wv][512+lane*4+e] = gB[e];
      #pragma unroll
      for (int e=0;e<4;e++) pP[wv][lane*4+e] = pA[e];
    }
    __syncthreads();
    {
      float sG = 0.f;
      #pragma unroll
      for (int w=0;w<8;w++) sG += pG[w][tid];
      gicW[(size_t)r2*H3 + tid] = f2b(sG);
      if (tid < 256){
        float sH = 0.f;
        #pragma unroll
        for (int w=0;w<8;w++) sH += pG[w][512+tid];
        gicW[(size_t)r2*H3 + 512 + tid] = f2b(sH);
      } else {
        int d = tid-256;
        float sP = 0.f;
        #pragma unroll
        for (int w=0;w<8;w++) sP += pP[w][d];
        pcW[(size_t)r2*HH + d] = f2b(sP);
      }
    }
  }
}

__global__ __launch_bounds__(256) void k_loss(const float* __restrict__ nll,
                                              float* __restrict__ out)
{
  __shared__ float sm[256];
  int tid=threadIdx.x;
  float s = nll[tid] + nll[tid+256];
  sm[tid]=s; __syncthreads();
  for (int off=128; off; off>>=1){
    if (tid<off) sm[tid]+=sm[tid+off];
    __syncthreads();
  }
  if (tid==0) out[0]=sm[0];
}

extern "C" void kernel_launch(void* const* d_in, const int* in_sizes, int n_in,
                              void* d_out, int out_size, void* d_ws, size_t ws_size,
                              hipStream_t stream)
{
  const int*   input    = (const int*)  d_in[0];
  const float* src_emb  = (const float*)d_in[1];
  const float* trg_emb  = (const float*)d_in[2];
  const float* eWih_f   = (const float*)d_in[3];
  const float* eWhh_f   = (const float*)d_in[4];
  const float* ebih_f   = (const float*)d_in[5];
  const float* ebhh_f   = (const float*)d_in[6];
  const float* eWih_b   = (const float*)d_in[7];
  const float* eWhh_b   = (const float*)d_in[8];
  const float* ebih_b   = (const float*)d_in[9];
  const float* ebhh_b   = (const float*)d_in[10];
  const float* bridge_W = (const float*)d_in[11];
  const float* bridge_b = (const float*)d_in[12];
  const float* attn_Wk  = (const float*)d_in[13];
  const float* attn_Wq  = (const float*)d_in[14];
  const float* attn_We  = (const float*)d_in[15];
  const float* dec_Wih  = (const float*)d_in[16];
  const float* dec_Whh  = (const float*)d_in[17];
  const float* dec_bih  = (const float*)d_in[18];
  const float* dec_bhh  = (const float*)d_in[19];
  const float* pre_W    = (const float*)d_in[20];
  const float* gen_W    = (const float*)d_in[21];

  float* F = (float*)d_ws;
  size_t o=0;
  u32* fl         = (u32*)(F+o); o+=2048;
  float* tab_gi_f = F+o; o+=(size_t)VV*H3;
  float* tab_gi_b = F+o; o+=(size_t)VV*H3;
  float* tab_dec  = F+o; o+=(size_t)VV*H3;
  float* tab_pre  = F+o; o+=(size_t)VV*HH;
  float* h_f      = F+o; o+=(size_t)BB*HH;
  float* h_b      = F+o; o+=(size_t)BB*HH;
  float* hst      = F+o; o+=(size_t)BB*HH;
  float* qg       = F+o; o+=(size_t)BB*HH;
  float* ghg      = F+o; o+=(size_t)BB*H3;
  float* nll      = F+o; o+=(size_t)BB;
  u16* U = (u16*)(F+o);
  size_t uo=0;
  u16* enc_out = U+uo; uo+=(size_t)BB*TT*H2;
  u16* pk      = U+uo; uo+=(size_t)BB*TT*HH;
  u16* eih     = U+uo; uo+=(size_t)BB*TT*H3;
  u16* epc     = U+uo; uo+=(size_t)BB*TT*HH;
  u16* gic0    = U+uo; uo+=(size_t)BB*H3;
  u16* gic1    = U+uo; uo+=(size_t)BB*H3;
  u16* pc0     = U+uo; uo+=(size_t)BB*HH;
  u16* pc1     = U+uo; uo+=(size_t)BB*HH;
  u16* wb_ehh_f= U+uo; uo+=(size_t)H3*HH;
  u16* wb_ehh_b= U+uo; uo+=(size_t)H3*HH;
  u16* wb_dhh  = U+uo; uo+=(size_t)H3*HH;
  u16* wb_dih  = U+uo; uo+=(size_t)H3*H2;
  u16* wb_wk   = U+uo; uo+=(size_t)HH*H2;
  u16* wb_wq   = U+uo; uo+=(size_t)HH*HH;
  u16* wb_ph   = U+uo; uo+=(size_t)HH*HH;
  u16* wb_pc   = U+uo; uo+=(size_t)HH*H2;
  u16* wb_gen  = U+uo; uo+=(size_t)64*HH;

  dim3 blk(256,1,1);
  k_tables<<<dim3(VV,10),blk,0,stream>>>(src_emb,trg_emb,eWih_f,ebih_f,eWih_b,ebih_b,
                                         dec_Wih,dec_bih,pre_W,
                                         tab_gi_f,tab_gi_b,tab_dec,tab_pre);
  k_cvt_all<<<dim3(5440),blk,0,stream>>>(eWhh_f,eWhh_b,dec_Whh,dec_Wih,attn_Wk,attn_Wq,pre_W,gen_W,
                                         wb_ehh_f,wb_ehh_b,wb_dhh,wb_dih,wb_wk,wb_wq,
                                         wb_ph,wb_pc,wb_gen);
  k_enc_all<<<dim3(128),dim3(512),0,stream>>>(input,wb_ehh_f,wb_ehh_b,ebhh_f,ebhh_b,
                                              tab_gi_f,tab_gi_b,h_f,h_b,enc_out);
  k_proj<<<dim3(1024,1),blk,0,stream>>>(enc_out,wb_wk,pk,HH);
  k_proj<<<dim3(1024,3),blk,0,stream>>>(enc_out,wb_dih,eih,H3);
  k_proj<<<dim3(1024,1),blk,0,stream>>>(enc_out,wb_pc,epc,HH);
  k_bridge<<<dim3(4,8),blk,0,stream>>>(h_f,h_b,bridge_W,bridge_b,hst);
  k_boot<<<dim3(32),blk,0,stream>>>(hst,wb_dhh,wb_wq,ghg,qg,nll);
  hipMemsetAsync(fl, 0, 8192, stream);

  for (int L=0; L<=TM1; L++){
    u16* gw = (L&1)? gic1 : gic0;
    u16* gr = (L&1)? gic0 : gic1;
    u16* pw = (L&1)? pc1 : pc0;
    u16* pr = (L&1)? pc0 : pc1;
    k_step<<<dim3(512),dim3(512),0,stream>>>(L,input,tab_dec,tab_pre,dec_bhh,attn_We,
                                             wb_dhh,wb_wq,wb_ph,wb_gen,
                                             pk,eih,epc,hst,(u32*)qg,ghg,
                                             gw,gr,pw,pr,nll,fl);
  }
  k_loss<<<dim3(1),blk,0,stream>>>(nll,(float*)d_out);
}